// Round 8
// baseline (550.663 us; speedup 1.0000x reference)
//
#include <hip/hip_runtime.h>
#include <hip/hip_bf16.h>

typedef __bf16 bf16x8 __attribute__((ext_vector_type(8)));
typedef unsigned short u16x8 __attribute__((ext_vector_type(8)));
typedef float f32x4 __attribute__((ext_vector_type(4)));

static constexpr int Bn = 2;
static constexpr int Tn = 2048;
static constexpr int En = 1024;
static constexpr int Hn = 16;
static constexpr int Dn = 64;
#define LOG2E 1.44269504088896340736f

static constexpr int SA = 40;  // 32-wide K tiles (80B rows, 16B-aligned)
static constexpr int SK = 72;  // 64-wide tiles (144B rows, 16B-aligned)

__device__ __forceinline__ unsigned short f2b(float x) {
  __hip_bfloat16 h = __float2bfloat16(x);
  return __builtin_bit_cast(unsigned short, h);
}
__device__ __forceinline__ float b2f(unsigned short u) {
  return __builtin_bit_cast(float, (unsigned)u << 16);
}
__device__ __forceinline__ bf16x8 ldb8(const unsigned short* p) {
  return __builtin_bit_cast(bf16x8, *reinterpret_cast<const u16x8*>(p));
}

// QKV GEMM in double-bf16: A,B (f32) split hi+lo at staging; 3 MFMA passes
// recover ~f32 fidelity. C[m,n] = sum_k A[m,k]*B[n,k]; scatter epilogue.
__global__ __launch_bounds__(256) void gemm_qkv_split(
    const float* __restrict__ A, const float* __restrict__ Bm,
    unsigned short* __restrict__ Qh, unsigned short* __restrict__ Ql,
    unsigned short* __restrict__ Kh, unsigned short* __restrict__ Kl,
    unsigned short* __restrict__ Vb, int M, int N, int K)
{
  __shared__ unsigned short shAh[128 * SA];
  __shared__ unsigned short shAl[128 * SA];
  __shared__ unsigned short shBh[128 * SA];
  __shared__ unsigned short shBl[128 * SA];
  const int tid = threadIdx.x;
  const int w = tid >> 6;
  const int L = tid & 63;
  const int qd = L >> 4;
  const int lr = L & 15;
  const int m0 = blockIdx.y * 128;
  const int n0 = blockIdx.x * 128;
  const int wm = (w >> 1) * 64;
  const int wn = (w & 1) * 64;

  f32x4 acc[4][4] = {};

  for (int k0 = 0; k0 < K; k0 += 32) {
#pragma unroll
    for (int p = 0; p < 4; ++p) {
      const int c = p * 256 + tid;
      const int row = c >> 3, slot = c & 7;
      const float4 va = *reinterpret_cast<const float4*>(
          A + (size_t)(m0 + row) * K + k0 + slot * 4);
      const float4 vb = *reinterpret_cast<const float4*>(
          Bm + (size_t)(n0 + row) * K + k0 + slot * 4);
      ushort4 ah, al, bh, bl;
      ah.x = f2b(va.x); al.x = f2b(va.x - b2f(ah.x));
      ah.y = f2b(va.y); al.y = f2b(va.y - b2f(ah.y));
      ah.z = f2b(va.z); al.z = f2b(va.z - b2f(ah.z));
      ah.w = f2b(va.w); al.w = f2b(va.w - b2f(ah.w));
      bh.x = f2b(vb.x); bl.x = f2b(vb.x - b2f(bh.x));
      bh.y = f2b(vb.y); bl.y = f2b(vb.y - b2f(bh.y));
      bh.z = f2b(vb.z); bl.z = f2b(vb.z - b2f(bh.z));
      bh.w = f2b(vb.w); bl.w = f2b(vb.w - b2f(bh.w));
      *reinterpret_cast<ushort4*>(&shAh[row * SA + slot * 4]) = ah;
      *reinterpret_cast<ushort4*>(&shAl[row * SA + slot * 4]) = al;
      *reinterpret_cast<ushort4*>(&shBh[row * SA + slot * 4]) = bh;
      *reinterpret_cast<ushort4*>(&shBl[row * SA + slot * 4]) = bl;
    }
    __syncthreads();

    bf16x8 afh[4], afl[4], bfh[4], bfl[4];
#pragma unroll
    for (int mt = 0; mt < 4; ++mt) {
      const int off = (wm + mt * 16 + lr) * SA + qd * 8;
      afh[mt] = ldb8(&shAh[off]);
      afl[mt] = ldb8(&shAl[off]);
    }
#pragma unroll
    for (int nt = 0; nt < 4; ++nt) {
      const int off = (wn + nt * 16 + lr) * SA + qd * 8;
      bfh[nt] = ldb8(&shBh[off]);
      bfl[nt] = ldb8(&shBl[off]);
    }
#pragma unroll
    for (int mt = 0; mt < 4; ++mt)
#pragma unroll
      for (int nt = 0; nt < 4; ++nt) {
        acc[mt][nt] = __builtin_amdgcn_mfma_f32_16x16x32_bf16(afh[mt], bfh[nt], acc[mt][nt], 0, 0, 0);
        acc[mt][nt] = __builtin_amdgcn_mfma_f32_16x16x32_bf16(afh[mt], bfl[nt], acc[mt][nt], 0, 0, 0);
        acc[mt][nt] = __builtin_amdgcn_mfma_f32_16x16x32_bf16(afl[mt], bfh[nt], acc[mt][nt], 0, 0, 0);
      }
    __syncthreads();
  }

  // C/D layout col=lane&15, row=(lane>>4)*4+reg
#pragma unroll
  for (int mt = 0; mt < 4; ++mt) {
#pragma unroll
    for (int nt = 0; nt < 4; ++nt) {
#pragma unroll
      for (int r = 0; r < 4; ++r) {
        const int m = m0 + wm + mt * 16 + qd * 4 + r;
        const int n = n0 + wn + nt * 16 + lr;
        const float val = acc[mt][nt][r];
        // einops '(d k h)': n = dd*48 + kk*16 + hh
        const int b = m >> 11, t = m & (Tn - 1);
        const int dd = n / 48;
        const int rem = n - dd * 48;
        const int kk = rem >> 4, hh = rem & 15;
        if (kk == 2) {
          Vb[((size_t)(b * Hn + hh) * Dn + dd) * Tn + t] = f2b(val);  // V as [b,h,d,t]
        } else {
          const unsigned short hi = f2b(val);
          const unsigned short lo = f2b(val - b2f(hi));
          const size_t idx = ((size_t)(b * Hn + hh) * Tn + t) * Dn + dd;
          if (kk == 0) { Qh[idx] = hi; Ql[idx] = lo; }
          else         { Kh[idx] = hi; Kl[idx] = lo; }
        }
      }
    }
  }
}

// Out-projection: OUT IS FLOAT32. C[m,n] = sum_k A[m,k]*B[n,k]; A bf16, B f32.
__global__ __launch_bounds__(256) void gemm_out(
    const unsigned short* __restrict__ A, const float* __restrict__ Bm,
    float* __restrict__ C, int M, int N, int K)
{
  __shared__ unsigned short shA[128 * SA];
  __shared__ unsigned short shB[128 * SA];
  const int tid = threadIdx.x;
  const int w = tid >> 6;
  const int L = tid & 63;
  const int qd = L >> 4;
  const int lr = L & 15;
  const int m0 = blockIdx.y * 128;
  const int n0 = blockIdx.x * 128;
  const int wm = (w >> 1) * 64;
  const int wn = (w & 1) * 64;

  f32x4 acc[4][4] = {};

  for (int k0 = 0; k0 < K; k0 += 32) {
#pragma unroll
    for (int p = 0; p < 2; ++p) {
      const int c = p * 256 + tid;
      const int row = c >> 2, slot = c & 3;
      *reinterpret_cast<u16x8*>(&shA[row * SA + slot * 8]) =
          *reinterpret_cast<const u16x8*>(A + (size_t)(m0 + row) * K + k0 + slot * 8);
    }
#pragma unroll
    for (int p = 0; p < 4; ++p) {
      const int c = p * 256 + tid;
      const int row = c >> 3, slot = c & 7;
      const float4 v = *reinterpret_cast<const float4*>(
          Bm + (size_t)(n0 + row) * K + k0 + slot * 4);
      ushort4 u;
      u.x = f2b(v.x); u.y = f2b(v.y); u.z = f2b(v.z); u.w = f2b(v.w);
      *reinterpret_cast<ushort4*>(&shB[row * SA + slot * 4]) = u;
    }
    __syncthreads();

    bf16x8 af[4], bf[4];
#pragma unroll
    for (int mt = 0; mt < 4; ++mt)
      af[mt] = ldb8(&shA[(wm + mt * 16 + lr) * SA + qd * 8]);
#pragma unroll
    for (int nt = 0; nt < 4; ++nt)
      bf[nt] = ldb8(&shB[(wn + nt * 16 + lr) * SA + qd * 8]);
#pragma unroll
    for (int mt = 0; mt < 4; ++mt)
#pragma unroll
      for (int nt = 0; nt < 4; ++nt)
        acc[mt][nt] = __builtin_amdgcn_mfma_f32_16x16x32_bf16(af[mt], bf[nt], acc[mt][nt], 0, 0, 0);
    __syncthreads();
  }

#pragma unroll
  for (int mt = 0; mt < 4; ++mt)
#pragma unroll
    for (int nt = 0; nt < 4; ++nt)
#pragma unroll
      for (int r = 0; r < 4; ++r) {
        const int m = m0 + wm + mt * 16 + qd * 4 + r;
        const int n = n0 + wn + nt * 16 + lr;
        C[(size_t)m * N + n] = acc[mt][nt][r];  // f32 store
      }
}

// Flash attention, double-bf16 energy: S = Qh·Kh + Qh·Kl + Ql·Kh.
// Qh/Ql,Kh/Kl: [b,h,t,d]  V: [b,h,d,t]  AO: [b,t,(h d)]
__global__ __launch_bounds__(256) void attn_kernel(
    const unsigned short* __restrict__ Qh, const unsigned short* __restrict__ Ql,
    const unsigned short* __restrict__ Kh, const unsigned short* __restrict__ Kl,
    const unsigned short* __restrict__ Vb, unsigned short* __restrict__ AO)
{
  __shared__ unsigned short shKh[64 * SK];
  __shared__ unsigned short shKl[64 * SK];
  __shared__ unsigned short shV[64 * SK];
  __shared__ unsigned short shP[4 * 16 * SK];
  const int tid = threadIdx.x;
  const int w = tid >> 6;
  const int L = tid & 63;
  const int qd = L >> 4;
  const int lr = L & 15;
  const int q0 = blockIdx.x * 64;
  const int bh = blockIdx.y;
  unsigned short* myP = &shP[w * 16 * SK];

  bf16x8 aqh[2], aql[2];
  {
    const size_t qoff = ((size_t)bh * Tn + q0 + w * 16 + lr) * Dn;
    aqh[0] = ldb8(Qh + qoff + qd * 8);
    aqh[1] = ldb8(Qh + qoff + 32 + qd * 8);
    aql[0] = ldb8(Ql + qoff + qd * 8);
    aql[1] = ldb8(Ql + qoff + 32 + qd * 8);
  }

  f32x4 oacc[4] = {};
  float mrow[4] = {-1e30f, -1e30f, -1e30f, -1e30f};
  float lsum[4] = {0.f, 0.f, 0.f, 0.f};

  for (int j0 = 0; j0 < Tn; j0 += 64) {
#pragma unroll
    for (int p = 0; p < 2; ++p) {
      const int c = p * 256 + tid;
      const int row = c >> 3, slot = c & 7;
      const size_t koff = ((size_t)bh * Tn + j0 + row) * Dn + slot * 8;
      *reinterpret_cast<u16x8*>(&shKh[row * SK + slot * 8]) =
          *reinterpret_cast<const u16x8*>(Kh + koff);
      *reinterpret_cast<u16x8*>(&shKl[row * SK + slot * 8]) =
          *reinterpret_cast<const u16x8*>(Kl + koff);
      *reinterpret_cast<u16x8*>(&shV[row * SK + slot * 8]) =
          *reinterpret_cast<const u16x8*>(Vb + ((size_t)bh * Dn + row) * Tn + j0 + slot * 8);
    }
    __syncthreads();

    f32x4 s[4] = {};
#pragma unroll
    for (int ct = 0; ct < 4; ++ct) {
      const int rk = ct * 16 + lr;
#pragma unroll
      for (int kc = 0; kc < 2; ++kc) {
        const int off = rk * SK + (kc * 4 + qd) * 8;
        const bf16x8 bkh = ldb8(&shKh[off]);
        const bf16x8 bkl = ldb8(&shKl[off]);
        s[ct] = __builtin_amdgcn_mfma_f32_16x16x32_bf16(aqh[kc], bkh, s[ct], 0, 0, 0);
        s[ct] = __builtin_amdgcn_mfma_f32_16x16x32_bf16(aqh[kc], bkl, s[ct], 0, 0, 0);
        s[ct] = __builtin_amdgcn_mfma_f32_16x16x32_bf16(aql[kc], bkh, s[ct], 0, 0, 0);
      }
    }
#pragma unroll
    for (int ct = 0; ct < 4; ++ct)
#pragma unroll
      for (int r = 0; r < 4; ++r)
        s[ct][r] = fminf(fmaxf(s[ct][r] * 8.0f, -1e30f), 1e30f);

    // raw S -> wave-private LDS (C-layout: row=qd*4+r, col=ct*16+lr)
#pragma unroll
    for (int ct = 0; ct < 4; ++ct)
#pragma unroll
      for (int r = 0; r < 4; ++r)
        myP[(qd * 4 + r) * SK + ct * 16 + lr] = f2b(s[ct][r]);

    // scan 1: row max
    float rm = -3e38f;
    {
      const u16x8 c0 = *reinterpret_cast<const u16x8*>(&myP[lr * SK + qd * 16]);
      const u16x8 c1 = *reinterpret_cast<const u16x8*>(&myP[lr * SK + qd * 16 + 8]);
#pragma unroll
      for (int j = 0; j < 8; ++j) rm = fmaxf(rm, fmaxf(b2f(c0[j]), b2f(c1[j])));
    }
    rm = fmaxf(rm, __shfl_xor(rm, 16, 64));
    rm = fmaxf(rm, __shfl_xor(rm, 32, 64));

    float alpha[4];
#pragma unroll
    for (int r = 0; r < 4; ++r) {
      const float Mt = __shfl(rm, qd * 4 + r, 64);
      const float mn = fmaxf(mrow[r], Mt);
      alpha[r] = exp2f((mrow[r] - mn) * LOG2E);
      mrow[r] = mn;
    }

#pragma unroll
    for (int ct = 0; ct < 4; ++ct)
#pragma unroll
      for (int r = 0; r < 4; ++r) {
        const float p = exp2f(fminf((s[ct][r] - mrow[r]) * LOG2E, 8.0f));
        myP[(qd * 4 + r) * SK + ct * 16 + lr] = f2b(p);
      }

    // scan 2: row sum over stored p
    float rs = 0.f;
    {
      const u16x8 c0 = *reinterpret_cast<const u16x8*>(&myP[lr * SK + qd * 16]);
      const u16x8 c1 = *reinterpret_cast<const u16x8*>(&myP[lr * SK + qd * 16 + 8]);
#pragma unroll
      for (int j = 0; j < 8; ++j) rs += b2f(c0[j]) + b2f(c1[j]);
    }
    rs += __shfl_xor(rs, 16, 64);
    rs += __shfl_xor(rs, 32, 64);

#pragma unroll
    for (int r = 0; r < 4; ++r) {
      const float Rs = __shfl(rs, qd * 4 + r, 64);
      lsum[r] = lsum[r] * alpha[r] + Rs;
    }
#pragma unroll
    for (int nt = 0; nt < 4; ++nt)
#pragma unroll
      for (int r = 0; r < 4; ++r)
        oacc[nt][r] = fminf(fmaxf(oacc[nt][r] * alpha[r], -1e30f), 1e30f);

    bf16x8 pa[2];
#pragma unroll
    for (int kc = 0; kc < 2; ++kc)
      pa[kc] = ldb8(&myP[lr * SK + (kc * 4 + qd) * 8]);
#pragma unroll
    for (int nt = 0; nt < 4; ++nt) {
      const int rv = nt * 16 + lr;
#pragma unroll
      for (int kc = 0; kc < 2; ++kc) {
        const bf16x8 bv = ldb8(&shV[rv * SK + (kc * 4 + qd) * 8]);
        oacc[nt] = __builtin_amdgcn_mfma_f32_16x16x32_bf16(pa[kc], bv, oacc[nt], 0, 0, 0);
      }
    }
    __syncthreads();
  }

  const int b = bh >> 4, h = bh & 15;
#pragma unroll
  for (int nt = 0; nt < 4; ++nt)
#pragma unroll
    for (int r = 0; r < 4; ++r) {
      const int trow = q0 + w * 16 + qd * 4 + r;
      const int col = h * 64 + nt * 16 + lr;
      float v = oacc[nt][r] / fmaxf(lsum[r], 1e-20f);
      v = fminf(fmaxf(v, -3e38f), 3e38f);
      AO[((size_t)b * Tn + trow) * En + col] = f2b(v);
    }
}

extern "C" void kernel_launch(void* const* d_in, const int* in_sizes, int n_in,
                              void* d_out, int out_size, void* d_ws, size_t ws_size,
                              hipStream_t stream) {
  (void)in_sizes; (void)n_in; (void)out_size; (void)ws_size;
  const float* x = (const float*)d_in[0];      // [2,2048,1024] f32
  const float* wqkv = (const float*)d_in[1];   // [3072,1024]  f32
  const float* wout = (const float*)d_in[2];   // [1024,1024]  f32
  float* out = (float*)d_out;                  // [2,2048,1024] f32  <-- the fix

  const size_t elems = (size_t)Bn * Hn * Tn * Dn;  // 4M elements = 8 MiB each
  unsigned short* Qh = (unsigned short*)d_ws;
  unsigned short* Ql = Qh + elems;
  unsigned short* Kh = Ql + elems;
  unsigned short* Kl = Kh + elems;
  unsigned short* Vb = Kl + elems;
  unsigned short* AOb = Vb + elems;  // total 48 MiB

  const int M = Bn * Tn;  // 4096
  dim3 blk(256);
  gemm_qkv_split<<<dim3(3 * En / 128, M / 128), blk, 0, stream>>>(
      x, wqkv, Qh, Ql, Kh, Kl, Vb, M, 3 * En, En);
  attn_kernel<<<dim3(Tn / 64, Bn * Hn), blk, 0, stream>>>(Qh, Ql, Kh, Kl, Vb, AOb);
  gemm_out<<<dim3(En / 128, M / 128), blk, 0, stream>>>(
      AOb, wout, out, M, En, En);
}

// Round 9
// 427.232 us; speedup vs baseline: 1.2889x; 1.2889x over previous
//
#include <hip/hip_runtime.h>
#include <hip/hip_bf16.h>

typedef __bf16 bf16x8 __attribute__((ext_vector_type(8)));
typedef unsigned short u16x8 __attribute__((ext_vector_type(8)));
typedef float f32x4 __attribute__((ext_vector_type(4)));

static constexpr int Bn = 2;
static constexpr int Tn = 2048;
static constexpr int En = 1024;
static constexpr int Hn = 16;
static constexpr int Dn = 64;
#define LOG2E 1.44269504088896340736f

static constexpr int SA = 40;   // 32-wide K tiles (80B rows, 16B-aligned)
static constexpr int SK = 72;   // 64-wide tiles (144B rows, 16B-aligned)
static constexpr int TS = 136;  // epilogue transpose stride (272B rows, 16B-aligned)

__device__ __forceinline__ unsigned short f2b(float x) {
  __hip_bfloat16 h = __float2bfloat16(x);
  return __builtin_bit_cast(unsigned short, h);
}
__device__ __forceinline__ float b2f(unsigned short u) {
  return __builtin_bit_cast(float, (unsigned)u << 16);
}
__device__ __forceinline__ bf16x8 ldb8(const unsigned short* p) {
  return __builtin_bit_cast(bf16x8, *reinterpret_cast<const u16x8*>(p));
}

// QKV GEMM, double-bf16, PERMUTED column tiling: block's columns are
// c' = kk*1024 + hh*64 + dd  (actual w_qkv row n = dd*48 + kk*16 + hh).
// kk is uniform per block -> epilogue does LDS transpose + coalesced 16B stores.
// Q is pre-scaled by 8 (folds the reference's *sqrt(d)).
__global__ __launch_bounds__(256) void gemm_qkv_split(
    const float* __restrict__ A, const float* __restrict__ Bm,
    unsigned short* __restrict__ Qh, unsigned short* __restrict__ Ql,
    unsigned short* __restrict__ Kh, unsigned short* __restrict__ Kl,
    unsigned short* __restrict__ Vb, int M, int K)
{
  __shared__ unsigned short smem[4 * 128 * SA];  // 40960 B; reused by epilogue
  unsigned short* shAh = smem;
  unsigned short* shAl = smem + 128 * SA;
  unsigned short* shBh = smem + 2 * 128 * SA;
  unsigned short* shBl = smem + 3 * 128 * SA;

  const int tid = threadIdx.x;
  const int w = tid >> 6;
  const int L = tid & 63;
  const int qd = L >> 4;
  const int lr = L & 15;
  const int m0 = blockIdx.y * 128;
  const int kk = blockIdx.x >> 3;          // 0=Q 1=K 2=V (uniform per block)
  const int hh0 = (blockIdx.x & 7) * 2;    // two heads per block
  const int wm = (w >> 1) * 64;
  const int wn = (w & 1) * 64;

  f32x4 acc[4][4] = {};

  for (int k0 = 0; k0 < K; k0 += 32) {
#pragma unroll
    for (int p = 0; p < 4; ++p) {
      const int c = p * 256 + tid;
      const int row = c >> 3, slot = c & 7;
      // A: x rows (contiguous). B: permuted w_qkv row for c'-row `row`.
      const int dd = row & 63, hl = row >> 6;
      const int nB = dd * 48 + kk * 16 + hh0 + hl;
      const float4 va = *reinterpret_cast<const float4*>(
          A + (size_t)(m0 + row) * K + k0 + slot * 4);
      const float4 vb = *reinterpret_cast<const float4*>(
          Bm + (size_t)nB * K + k0 + slot * 4);
      ushort4 ah, al, bh, bl;
      ah.x = f2b(va.x); al.x = f2b(va.x - b2f(ah.x));
      ah.y = f2b(va.y); al.y = f2b(va.y - b2f(ah.y));
      ah.z = f2b(va.z); al.z = f2b(va.z - b2f(ah.z));
      ah.w = f2b(va.w); al.w = f2b(va.w - b2f(ah.w));
      bh.x = f2b(vb.x); bl.x = f2b(vb.x - b2f(bh.x));
      bh.y = f2b(vb.y); bl.y = f2b(vb.y - b2f(bh.y));
      bh.z = f2b(vb.z); bl.z = f2b(vb.z - b2f(bh.z));
      bh.w = f2b(vb.w); bl.w = f2b(vb.w - b2f(bh.w));
      *reinterpret_cast<ushort4*>(&shAh[row * SA + slot * 4]) = ah;
      *reinterpret_cast<ushort4*>(&shAl[row * SA + slot * 4]) = al;
      *reinterpret_cast<ushort4*>(&shBh[row * SA + slot * 4]) = bh;
      *reinterpret_cast<ushort4*>(&shBl[row * SA + slot * 4]) = bl;
    }
    __syncthreads();

    bf16x8 afh[4], afl[4], bfh[4], bfl[4];
#pragma unroll
    for (int mt = 0; mt < 4; ++mt) {
      const int off = (wm + mt * 16 + lr) * SA + qd * 8;
      afh[mt] = ldb8(&shAh[off]);
      afl[mt] = ldb8(&shAl[off]);
    }
#pragma unroll
    for (int nt = 0; nt < 4; ++nt) {
      const int off = (wn + nt * 16 + lr) * SA + qd * 8;
      bfh[nt] = ldb8(&shBh[off]);
      bfl[nt] = ldb8(&shBl[off]);
    }
#pragma unroll
    for (int mt = 0; mt < 4; ++mt)
#pragma unroll
      for (int nt = 0; nt < 4; ++nt) {
        acc[mt][nt] = __builtin_amdgcn_mfma_f32_16x16x32_bf16(afh[mt], bfh[nt], acc[mt][nt], 0, 0, 0);
        acc[mt][nt] = __builtin_amdgcn_mfma_f32_16x16x32_bf16(afh[mt], bfl[nt], acc[mt][nt], 0, 0, 0);
        acc[mt][nt] = __builtin_amdgcn_mfma_f32_16x16x32_bf16(afl[mt], bfh[nt], acc[mt][nt], 0, 0, 0);
      }
    __syncthreads();
  }

  // ---- epilogue: LDS transpose -> coalesced 16B stores ----
  const int b = m0 >> 11;
  const int t0 = m0 & (Tn - 1);
  const float qscale = (kk == 0) ? 8.0f : 1.0f;  // fold *sqrt(d) into Q
  const int npass = (kk == 2) ? 1 : 2;

  for (int pass = 0; pass < npass; ++pass) {
#pragma unroll
    for (int mt = 0; mt < 4; ++mt)
#pragma unroll
      for (int nt = 0; nt < 4; ++nt)
#pragma unroll
        for (int r = 0; r < 4; ++r) {
          const int ml = wm + mt * 16 + qd * 4 + r;  // C/D row=(lane>>4)*4+reg
          const int cl = wn + nt * 16 + lr;          // C/D col=lane&15
          const float val = acc[mt][nt][r] * qscale;
          unsigned short v;
          if (kk == 2) {
            v = f2b(val);
          } else {
            const unsigned short hi = f2b(val);
            v = (pass == 0) ? hi : f2b(val - b2f(hi));
          }
          smem[ml * TS + cl] = v;
        }
    __syncthreads();

    unsigned short* dst = (kk == 0) ? (pass == 0 ? Qh : Ql)
                        : (kk == 1) ? (pass == 0 ? Kh : Kl) : Vb;
    if (kk < 2) {
      // Q/K [b,h,t,d]: contiguous along dd
#pragma unroll
      for (int p = 0; p < 8; ++p) {
        const int s = p * 256 + tid;
        const int tl = s >> 4, sub = s & 15;
        const int hl = sub >> 3, oct = sub & 7;
        const u16x8 v = *reinterpret_cast<const u16x8*>(&smem[tl * TS + hl * 64 + oct * 8]);
        *reinterpret_cast<u16x8*>(
            dst + ((size_t)(b * Hn + hh0 + hl) * Tn + t0 + tl) * Dn + oct * 8) = v;
      }
    } else {
      // V [b,h,d,t]: contiguous along t (column gather from LDS)
#pragma unroll
      for (int p = 0; p < 8; ++p) {
        const int s = p * 256 + tid;
        const int cl = s >> 4, oct = s & 15;
        const int hl = cl >> 6, dd = cl & 63;
        u16x8 v;
#pragma unroll
        for (int j = 0; j < 8; ++j) v[j] = smem[(oct * 8 + j) * TS + cl];
        *reinterpret_cast<u16x8*>(
            dst + ((size_t)((b * Hn + hh0 + hl) * Dn + dd)) * Tn + t0 + oct * 8) = v;
      }
    }
    __syncthreads();
  }
}

// Out-projection: OUT f32. C[m,n] = sum_k A[m,k]*B[n,k]; A bf16, B f32.
__global__ __launch_bounds__(256) void gemm_out(
    const unsigned short* __restrict__ A, const float* __restrict__ Bm,
    float* __restrict__ C, int M, int N, int K)
{
  __shared__ unsigned short shA[128 * SA];
  __shared__ unsigned short shB[128 * SA];
  const int tid = threadIdx.x;
  const int w = tid >> 6;
  const int L = tid & 63;
  const int qd = L >> 4;
  const int lr = L & 15;
  const int m0 = blockIdx.y * 128;
  const int n0 = blockIdx.x * 128;
  const int wm = (w >> 1) * 64;
  const int wn = (w & 1) * 64;

  f32x4 acc[4][4] = {};

  for (int k0 = 0; k0 < K; k0 += 32) {
#pragma unroll
    for (int p = 0; p < 2; ++p) {
      const int c = p * 256 + tid;
      const int row = c >> 2, slot = c & 3;
      *reinterpret_cast<u16x8*>(&shA[row * SA + slot * 8]) =
          *reinterpret_cast<const u16x8*>(A + (size_t)(m0 + row) * K + k0 + slot * 8);
    }
#pragma unroll
    for (int p = 0; p < 4; ++p) {
      const int c = p * 256 + tid;
      const int row = c >> 3, slot = c & 7;
      const float4 v = *reinterpret_cast<const float4*>(
          Bm + (size_t)(n0 + row) * K + k0 + slot * 4);
      ushort4 u;
      u.x = f2b(v.x); u.y = f2b(v.y); u.z = f2b(v.z); u.w = f2b(v.w);
      *reinterpret_cast<ushort4*>(&shB[row * SA + slot * 4]) = u;
    }
    __syncthreads();

    bf16x8 af[4], bf[4];
#pragma unroll
    for (int mt = 0; mt < 4; ++mt)
      af[mt] = ldb8(&shA[(wm + mt * 16 + lr) * SA + qd * 8]);
#pragma unroll
    for (int nt = 0; nt < 4; ++nt)
      bf[nt] = ldb8(&shB[(wn + nt * 16 + lr) * SA + qd * 8]);
#pragma unroll
    for (int mt = 0; mt < 4; ++mt)
#pragma unroll
      for (int nt = 0; nt < 4; ++nt)
        acc[mt][nt] = __builtin_amdgcn_mfma_f32_16x16x32_bf16(af[mt], bf[nt], acc[mt][nt], 0, 0, 0);
    __syncthreads();
  }

#pragma unroll
  for (int mt = 0; mt < 4; ++mt)
#pragma unroll
    for (int nt = 0; nt < 4; ++nt)
#pragma unroll
      for (int r = 0; r < 4; ++r) {
        const int m = m0 + wm + mt * 16 + qd * 4 + r;
        const int n = n0 + wn + nt * 16 + lr;
        C[(size_t)m * N + n] = acc[mt][nt][r];
      }
}

// Flash attention, double-bf16 energy, register softmax stats.
// Qh/Ql (pre-scaled by 8), Kh/Kl: [b,h,t,d]  V: [b,h,d,t]  AO: [b,t,(h d)]
__global__ __launch_bounds__(256) void attn_kernel(
    const unsigned short* __restrict__ Qh, const unsigned short* __restrict__ Ql,
    const unsigned short* __restrict__ Kh, const unsigned short* __restrict__ Kl,
    const unsigned short* __restrict__ Vb, unsigned short* __restrict__ AO)
{
  __shared__ unsigned short shKh[64 * SK];
  __shared__ unsigned short shKl[64 * SK];
  __shared__ unsigned short shV[64 * SK];
  __shared__ unsigned short shP[4 * 16 * SK];
  const int tid = threadIdx.x;
  const int w = tid >> 6;
  const int L = tid & 63;
  const int qd = L >> 4;
  const int lr = L & 15;
  const int q0 = blockIdx.x * 64;
  const int bh = blockIdx.y;
  unsigned short* myP = &shP[w * 16 * SK];

  bf16x8 aqh[2], aql[2];
  {
    const size_t qoff = ((size_t)bh * Tn + q0 + w * 16 + lr) * Dn;
    aqh[0] = ldb8(Qh + qoff + qd * 8);
    aqh[1] = ldb8(Qh + qoff + 32 + qd * 8);
    aql[0] = ldb8(Ql + qoff + qd * 8);
    aql[1] = ldb8(Ql + qoff + 32 + qd * 8);
  }

  f32x4 oacc[4] = {};
  float mrow[4] = {-1e30f, -1e30f, -1e30f, -1e30f};
  float lsum[4] = {0.f, 0.f, 0.f, 0.f};

  for (int j0 = 0; j0 < Tn; j0 += 64) {
#pragma unroll
    for (int p = 0; p < 2; ++p) {
      const int c = p * 256 + tid;
      const int row = c >> 3, slot = c & 7;
      const size_t koff = ((size_t)bh * Tn + j0 + row) * Dn + slot * 8;
      *reinterpret_cast<u16x8*>(&shKh[row * SK + slot * 8]) =
          *reinterpret_cast<const u16x8*>(Kh + koff);
      *reinterpret_cast<u16x8*>(&shKl[row * SK + slot * 8]) =
          *reinterpret_cast<const u16x8*>(Kl + koff);
      *reinterpret_cast<u16x8*>(&shV[row * SK + slot * 8]) =
          *reinterpret_cast<const u16x8*>(Vb + ((size_t)bh * Dn + row) * Tn + j0 + slot * 8);
    }
    __syncthreads();

    // S = Q K^T (Q pre-scaled by 8); 3 MFMA per frag pair for ~f32 fidelity
    f32x4 s[4] = {};
#pragma unroll
    for (int ct = 0; ct < 4; ++ct) {
      const int rk = ct * 16 + lr;
#pragma unroll
      for (int kc = 0; kc < 2; ++kc) {
        const int off = rk * SK + (kc * 4 + qd) * 8;
        const bf16x8 bkh = ldb8(&shKh[off]);
        const bf16x8 bkl = ldb8(&shKl[off]);
        s[ct] = __builtin_amdgcn_mfma_f32_16x16x32_bf16(aqh[kc], bkh, s[ct], 0, 0, 0);
        s[ct] = __builtin_amdgcn_mfma_f32_16x16x32_bf16(aqh[kc], bkl, s[ct], 0, 0, 0);
        s[ct] = __builtin_amdgcn_mfma_f32_16x16x32_bf16(aql[kc], bkh, s[ct], 0, 0, 0);
      }
    }

    // register softmax stats: row qd*4+r owned by the 16 lanes of this qd group
    float tmax[4];
#pragma unroll
    for (int r = 0; r < 4; ++r)
      tmax[r] = fmaxf(fmaxf(s[0][r], s[1][r]), fmaxf(s[2][r], s[3][r]));
#pragma unroll
    for (int x = 1; x < 16; x <<= 1)
#pragma unroll
      for (int r = 0; r < 4; ++r) tmax[r] = fmaxf(tmax[r], __shfl_xor(tmax[r], x, 64));

    float alpha[4], rsum[4];
#pragma unroll
    for (int r = 0; r < 4; ++r) {
      const float mn = fmaxf(mrow[r], tmax[r]);
      alpha[r] = exp2f((mrow[r] - mn) * LOG2E);
      mrow[r] = mn;
      rsum[r] = 0.f;
    }
#pragma unroll
    for (int ct = 0; ct < 4; ++ct)
#pragma unroll
      for (int r = 0; r < 4; ++r) {
        const float p = exp2f((s[ct][r] - mrow[r]) * LOG2E);  // arg <= 0
        s[ct][r] = p;
        rsum[r] += p;
      }
#pragma unroll
    for (int x = 1; x < 16; x <<= 1)
#pragma unroll
      for (int r = 0; r < 4; ++r) rsum[r] += __shfl_xor(rsum[r], x, 64);
#pragma unroll
    for (int r = 0; r < 4; ++r) lsum[r] = lsum[r] * alpha[r] + rsum[r];
#pragma unroll
    for (int nt = 0; nt < 4; ++nt)
#pragma unroll
      for (int r = 0; r < 4; ++r) oacc[nt][r] *= alpha[r];

    // P (C-layout) -> wave-private LDS -> A-layout frags
#pragma unroll
    for (int ct = 0; ct < 4; ++ct)
#pragma unroll
      for (int r = 0; r < 4; ++r)
        myP[(qd * 4 + r) * SK + ct * 16 + lr] = f2b(s[ct][r]);

    bf16x8 pa[2];
#pragma unroll
    for (int kc = 0; kc < 2; ++kc)
      pa[kc] = ldb8(&myP[lr * SK + (kc * 4 + qd) * 8]);
#pragma unroll
    for (int nt = 0; nt < 4; ++nt) {
      const int rv = nt * 16 + lr;
#pragma unroll
      for (int kc = 0; kc < 2; ++kc) {
        const bf16x8 bv = ldb8(&shV[rv * SK + (kc * 4 + qd) * 8]);
        oacc[nt] = __builtin_amdgcn_mfma_f32_16x16x32_bf16(pa[kc], bv, oacc[nt], 0, 0, 0);
      }
    }
    __syncthreads();
  }

  const int b = bh >> 4, h = bh & 15;
#pragma unroll
  for (int nt = 0; nt < 4; ++nt)
#pragma unroll
    for (int r = 0; r < 4; ++r) {
      const int trow = q0 + w * 16 + qd * 4 + r;
      const int col = h * 64 + nt * 16 + lr;
      AO[((size_t)b * Tn + trow) * En + col] = f2b(oacc[nt][r] / lsum[r]);
    }
}

extern "C" void kernel_launch(void* const* d_in, const int* in_sizes, int n_in,
                              void* d_out, int out_size, void* d_ws, size_t ws_size,
                              hipStream_t stream) {
  (void)in_sizes; (void)n_in; (void)out_size; (void)ws_size;
  const float* x = (const float*)d_in[0];      // [2,2048,1024] f32
  const float* wqkv = (const float*)d_in[1];   // [3072,1024]  f32
  const float* wout = (const float*)d_in[2];   // [1024,1024]  f32
  float* out = (float*)d_out;                  // [2,2048,1024] f32

  const size_t elems = (size_t)Bn * Hn * Tn * Dn;  // 4M elements = 8 MiB each
  unsigned short* Qh = (unsigned short*)d_ws;
  unsigned short* Ql = Qh + elems;
  unsigned short* Kh = Ql + elems;
  unsigned short* Kl = Kh + elems;
  unsigned short* Vb = Kl + elems;
  unsigned short* AOb = Vb + elems;  // total 48 MiB

  const int M = Bn * Tn;  // 4096
  dim3 blk(256);
  gemm_qkv_split<<<dim3(24, M / 128), blk, 0, stream>>>(
      x, wqkv, Qh, Ql, Kh, Kl, Vb, M, En);
  attn_kernel<<<dim3(Tn / 64, Bn * Hn), blk, 0, stream>>>(Qh, Ql, Kh, Kl, Vb, AOb);
  gemm_out<<<dim3(En / 128, M / 128), blk, 0, stream>>>(
      AOb, wout, out, M, En, En);
}

// Round 10
// 406.175 us; speedup vs baseline: 1.3557x; 1.0518x over previous
//
#include <hip/hip_runtime.h>
#include <hip/hip_bf16.h>

typedef __bf16 bf16x8 __attribute__((ext_vector_type(8)));
typedef unsigned short u16x8 __attribute__((ext_vector_type(8)));
typedef float f32x4 __attribute__((ext_vector_type(4)));

static constexpr int Bn = 2;
static constexpr int Tn = 2048;
static constexpr int En = 1024;
static constexpr int Hn = 16;
static constexpr int Dn = 64;
#define LOG2E 1.44269504088896340736f

static constexpr int SA = 40;   // 32-wide K tiles (80B rows, 16B-aligned)
static constexpr int SK = 72;   // 64-wide tiles (144B rows, 16B-aligned)
static constexpr int TS = 136;  // epilogue transpose stride (272B rows, 16B-aligned)

__device__ __forceinline__ unsigned short f2b(float x) {
  __hip_bfloat16 h = __float2bfloat16(x);
  return __builtin_bit_cast(unsigned short, h);
}
__device__ __forceinline__ float b2f(unsigned short u) {
  return __builtin_bit_cast(float, (unsigned)u << 16);
}
__device__ __forceinline__ bf16x8 ldb8(const unsigned short* p) {
  return __builtin_bit_cast(bf16x8, *reinterpret_cast<const u16x8*>(p));
}

// One-shot hi/lo bf16 split of an f32 array (hoisted out of the GEMM k-loop).
__global__ __launch_bounds__(256) void split_f32_bf16(
    const float* __restrict__ src, unsigned short* __restrict__ hi,
    unsigned short* __restrict__ lo)
{
  const int i = (blockIdx.x * 256 + threadIdx.x) * 4;
  const float4 v = *reinterpret_cast<const float4*>(src + i);
  ushort4 h, l;
  h.x = f2b(v.x); l.x = f2b(v.x - b2f(h.x));
  h.y = f2b(v.y); l.y = f2b(v.y - b2f(h.y));
  h.z = f2b(v.z); l.z = f2b(v.z - b2f(h.z));
  h.w = f2b(v.w); l.w = f2b(v.w - b2f(h.w));
  *reinterpret_cast<ushort4*>(hi + i) = h;
  *reinterpret_cast<ushort4*>(lo + i) = l;
}

// QKV GEMM, double-bf16 from PRE-SPLIT operands; permuted column tiling
// c' = kk*1024 + hh*64 + dd (w_qkv row n = dd*48 + kk*16 + hh); kk uniform
// per block -> LDS-transpose epilogue, coalesced 16B stores. Q pre-scaled x8.
__global__ __launch_bounds__(256) void gemm_qkv_split(
    const unsigned short* __restrict__ xh, const unsigned short* __restrict__ xl,
    const unsigned short* __restrict__ wh, const unsigned short* __restrict__ wl,
    unsigned short* __restrict__ Qh, unsigned short* __restrict__ Ql,
    unsigned short* __restrict__ Kh, unsigned short* __restrict__ Kl,
    unsigned short* __restrict__ Vb, int M, int K)
{
  __shared__ unsigned short smem[4 * 128 * SA];  // 40960 B; reused by epilogue
  unsigned short* shAh = smem;
  unsigned short* shAl = smem + 128 * SA;
  unsigned short* shBh = smem + 2 * 128 * SA;
  unsigned short* shBl = smem + 3 * 128 * SA;

  const int tid = threadIdx.x;
  const int w = tid >> 6;
  const int L = tid & 63;
  const int qd = L >> 4;
  const int lr = L & 15;
  const int m0 = blockIdx.y * 128;
  const int kk = blockIdx.x >> 3;          // 0=Q 1=K 2=V (uniform per block)
  const int hh0 = (blockIdx.x & 7) * 2;    // two heads per block
  const int wm = (w >> 1) * 64;
  const int wn = (w & 1) * 64;

  f32x4 acc[4][4] = {};

  for (int k0 = 0; k0 < K; k0 += 32) {
#pragma unroll
    for (int p = 0; p < 2; ++p) {
      const int c = p * 256 + tid;            // 512 16B-chunks per tile
      const int row = c >> 2, slot = c & 3;
      const int dd = row & 63, hl = row >> 6;
      const int nB = dd * 48 + kk * 16 + hh0 + hl;
      const size_t aoff = (size_t)(m0 + row) * K + k0 + slot * 8;
      const size_t boff = (size_t)nB * K + k0 + slot * 8;
      *reinterpret_cast<u16x8*>(&shAh[row * SA + slot * 8]) =
          *reinterpret_cast<const u16x8*>(xh + aoff);
      *reinterpret_cast<u16x8*>(&shAl[row * SA + slot * 8]) =
          *reinterpret_cast<const u16x8*>(xl + aoff);
      *reinterpret_cast<u16x8*>(&shBh[row * SA + slot * 8]) =
          *reinterpret_cast<const u16x8*>(wh + boff);
      *reinterpret_cast<u16x8*>(&shBl[row * SA + slot * 8]) =
          *reinterpret_cast<const u16x8*>(wl + boff);
    }
    __syncthreads();

    bf16x8 afh[4], afl[4], bfh[4], bfl[4];
#pragma unroll
    for (int mt = 0; mt < 4; ++mt) {
      const int off = (wm + mt * 16 + lr) * SA + qd * 8;
      afh[mt] = ldb8(&shAh[off]);
      afl[mt] = ldb8(&shAl[off]);
    }
#pragma unroll
    for (int nt = 0; nt < 4; ++nt) {
      const int off = (wn + nt * 16 + lr) * SA + qd * 8;
      bfh[nt] = ldb8(&shBh[off]);
      bfl[nt] = ldb8(&shBl[off]);
    }
#pragma unroll
    for (int mt = 0; mt < 4; ++mt)
#pragma unroll
      for (int nt = 0; nt < 4; ++nt) {
        acc[mt][nt] = __builtin_amdgcn_mfma_f32_16x16x32_bf16(afh[mt], bfh[nt], acc[mt][nt], 0, 0, 0);
        acc[mt][nt] = __builtin_amdgcn_mfma_f32_16x16x32_bf16(afh[mt], bfl[nt], acc[mt][nt], 0, 0, 0);
        acc[mt][nt] = __builtin_amdgcn_mfma_f32_16x16x32_bf16(afl[mt], bfh[nt], acc[mt][nt], 0, 0, 0);
      }
    __syncthreads();
  }

  // ---- epilogue: LDS transpose -> coalesced 16B stores ----
  const int b = m0 >> 11;
  const int t0 = m0 & (Tn - 1);
  const float qscale = (kk == 0) ? 8.0f : 1.0f;  // fold *sqrt(d) into Q
  const int npass = (kk == 2) ? 1 : 2;

  for (int pass = 0; pass < npass; ++pass) {
#pragma unroll
    for (int mt = 0; mt < 4; ++mt)
#pragma unroll
      for (int nt = 0; nt < 4; ++nt)
#pragma unroll
        for (int r = 0; r < 4; ++r) {
          const int ml = wm + mt * 16 + qd * 4 + r;  // C/D row=(lane>>4)*4+reg
          const int cl = wn + nt * 16 + lr;          // C/D col=lane&15
          const float val = acc[mt][nt][r] * qscale;
          unsigned short v;
          if (kk == 2) {
            v = f2b(val);
          } else {
            const unsigned short hi = f2b(val);
            v = (pass == 0) ? hi : f2b(val - b2f(hi));
          }
          smem[ml * TS + cl] = v;
        }
    __syncthreads();

    unsigned short* dst = (kk == 0) ? (pass == 0 ? Qh : Ql)
                        : (kk == 1) ? (pass == 0 ? Kh : Kl) : Vb;
    if (kk < 2) {
      // Q/K [b,h,t,d]: contiguous along dd
#pragma unroll
      for (int p = 0; p < 8; ++p) {
        const int s = p * 256 + tid;
        const int tl = s >> 4, sub = s & 15;
        const int hl = sub >> 3, oct = sub & 7;
        const u16x8 v = *reinterpret_cast<const u16x8*>(&smem[tl * TS + hl * 64 + oct * 8]);
        *reinterpret_cast<u16x8*>(
            dst + ((size_t)(b * Hn + hh0 + hl) * Tn + t0 + tl) * Dn + oct * 8) = v;
      }
    } else {
      // V [b,h,d,t]: contiguous along t (column gather from LDS)
#pragma unroll
      for (int p = 0; p < 8; ++p) {
        const int s = p * 256 + tid;
        const int cl = s >> 4, oct = s & 15;
        const int hl = cl >> 6, dd = cl & 63;
        u16x8 v;
#pragma unroll
        for (int j = 0; j < 8; ++j) v[j] = smem[(oct * 8 + j) * TS + cl];
        *reinterpret_cast<u16x8*>(
            dst + ((size_t)((b * Hn + hh0 + hl) * Dn + dd)) * Tn + t0 + oct * 8) = v;
      }
    }
    __syncthreads();
  }
}

// Out-projection: OUT f32. C[m,n] = sum_k A[m,k]*B[n,k]; A bf16, B f32.
__global__ __launch_bounds__(256) void gemm_out(
    const unsigned short* __restrict__ A, const float* __restrict__ Bm,
    float* __restrict__ C, int M, int N, int K)
{
  __shared__ unsigned short shA[128 * SA];
  __shared__ unsigned short shB[128 * SA];
  const int tid = threadIdx.x;
  const int w = tid >> 6;
  const int L = tid & 63;
  const int qd = L >> 4;
  const int lr = L & 15;
  const int m0 = blockIdx.y * 128;
  const int n0 = blockIdx.x * 128;
  const int wm = (w >> 1) * 64;
  const int wn = (w & 1) * 64;

  f32x4 acc[4][4] = {};

  for (int k0 = 0; k0 < K; k0 += 32) {
#pragma unroll
    for (int p = 0; p < 2; ++p) {
      const int c = p * 256 + tid;
      const int row = c >> 2, slot = c & 3;
      *reinterpret_cast<u16x8*>(&shA[row * SA + slot * 8]) =
          *reinterpret_cast<const u16x8*>(A + (size_t)(m0 + row) * K + k0 + slot * 8);
    }
#pragma unroll
    for (int p = 0; p < 4; ++p) {
      const int c = p * 256 + tid;
      const int row = c >> 3, slot = c & 7;
      const float4 v = *reinterpret_cast<const float4*>(
          Bm + (size_t)(n0 + row) * K + k0 + slot * 4);
      ushort4 u;
      u.x = f2b(v.x); u.y = f2b(v.y); u.z = f2b(v.z); u.w = f2b(v.w);
      *reinterpret_cast<ushort4*>(&shB[row * SA + slot * 4]) = u;
    }
    __syncthreads();

    bf16x8 af[4], bf[4];
#pragma unroll
    for (int mt = 0; mt < 4; ++mt)
      af[mt] = ldb8(&shA[(wm + mt * 16 + lr) * SA + qd * 8]);
#pragma unroll
    for (int nt = 0; nt < 4; ++nt)
      bf[nt] = ldb8(&shB[(wn + nt * 16 + lr) * SA + qd * 8]);
#pragma unroll
    for (int mt = 0; mt < 4; ++mt)
#pragma unroll
      for (int nt = 0; nt < 4; ++nt)
        acc[mt][nt] = __builtin_amdgcn_mfma_f32_16x16x32_bf16(af[mt], bf[nt], acc[mt][nt], 0, 0, 0);
    __syncthreads();
  }

#pragma unroll
  for (int mt = 0; mt < 4; ++mt)
#pragma unroll
    for (int nt = 0; nt < 4; ++nt)
#pragma unroll
      for (int r = 0; r < 4; ++r) {
        const int m = m0 + wm + mt * 16 + qd * 4 + r;
        const int n = n0 + wn + nt * 16 + lr;
        C[(size_t)m * N + n] = acc[mt][nt][r];
      }
}

// Flash attention, double-bf16 energy, register softmax stats.
// Qh/Ql (pre-scaled by 8), Kh/Kl: [b,h,t,d]  V: [b,h,d,t]  AO: [b,t,(h d)]
__global__ __launch_bounds__(256) void attn_kernel(
    const unsigned short* __restrict__ Qh, const unsigned short* __restrict__ Ql,
    const unsigned short* __restrict__ Kh, const unsigned short* __restrict__ Kl,
    const unsigned short* __restrict__ Vb, unsigned short* __restrict__ AO)
{
  __shared__ unsigned short shKh[64 * SK];
  __shared__ unsigned short shKl[64 * SK];
  __shared__ unsigned short shV[64 * SK];
  __shared__ unsigned short shP[4 * 16 * SK];
  const int tid = threadIdx.x;
  const int w = tid >> 6;
  const int L = tid & 63;
  const int qd = L >> 4;
  const int lr = L & 15;
  const int q0 = blockIdx.x * 64;
  const int bh = blockIdx.y;
  unsigned short* myP = &shP[w * 16 * SK];

  bf16x8 aqh[2], aql[2];
  {
    const size_t qoff = ((size_t)bh * Tn + q0 + w * 16 + lr) * Dn;
    aqh[0] = ldb8(Qh + qoff + qd * 8);
    aqh[1] = ldb8(Qh + qoff + 32 + qd * 8);
    aql[0] = ldb8(Ql + qoff + qd * 8);
    aql[1] = ldb8(Ql + qoff + 32 + qd * 8);
  }

  f32x4 oacc[4] = {};
  float mrow[4] = {-1e30f, -1e30f, -1e30f, -1e30f};
  float lsum[4] = {0.f, 0.f, 0.f, 0.f};

  for (int j0 = 0; j0 < Tn; j0 += 64) {
#pragma unroll
    for (int p = 0; p < 2; ++p) {
      const int c = p * 256 + tid;
      const int row = c >> 3, slot = c & 7;
      const size_t koff = ((size_t)bh * Tn + j0 + row) * Dn + slot * 8;
      *reinterpret_cast<u16x8*>(&shKh[row * SK + slot * 8]) =
          *reinterpret_cast<const u16x8*>(Kh + koff);
      *reinterpret_cast<u16x8*>(&shKl[row * SK + slot * 8]) =
          *reinterpret_cast<const u16x8*>(Kl + koff);
      *reinterpret_cast<u16x8*>(&shV[row * SK + slot * 8]) =
          *reinterpret_cast<const u16x8*>(Vb + ((size_t)bh * Dn + row) * Tn + j0 + slot * 8);
    }
    __syncthreads();

    // S = Q K^T (Q pre-scaled by 8); 3 MFMA per frag pair for ~f32 fidelity
    f32x4 s[4] = {};
#pragma unroll
    for (int ct = 0; ct < 4; ++ct) {
      const int rk = ct * 16 + lr;
#pragma unroll
      for (int kc = 0; kc < 2; ++kc) {
        const int off = rk * SK + (kc * 4 + qd) * 8;
        const bf16x8 bkh = ldb8(&shKh[off]);
        const bf16x8 bkl = ldb8(&shKl[off]);
        s[ct] = __builtin_amdgcn_mfma_f32_16x16x32_bf16(aqh[kc], bkh, s[ct], 0, 0, 0);
        s[ct] = __builtin_amdgcn_mfma_f32_16x16x32_bf16(aqh[kc], bkl, s[ct], 0, 0, 0);
        s[ct] = __builtin_amdgcn_mfma_f32_16x16x32_bf16(aql[kc], bkh, s[ct], 0, 0, 0);
      }
    }

    // register softmax stats: row qd*4+r owned by the 16 lanes of this qd group
    float tmax[4];
#pragma unroll
    for (int r = 0; r < 4; ++r)
      tmax[r] = fmaxf(fmaxf(s[0][r], s[1][r]), fmaxf(s[2][r], s[3][r]));
#pragma unroll
    for (int x = 1; x < 16; x <<= 1)
#pragma unroll
      for (int r = 0; r < 4; ++r) tmax[r] = fmaxf(tmax[r], __shfl_xor(tmax[r], x, 64));

    float alpha[4], rsum[4];
#pragma unroll
    for (int r = 0; r < 4; ++r) {
      const float mn = fmaxf(mrow[r], tmax[r]);
      alpha[r] = exp2f((mrow[r] - mn) * LOG2E);
      mrow[r] = mn;
      rsum[r] = 0.f;
    }
#pragma unroll
    for (int ct = 0; ct < 4; ++ct)
#pragma unroll
      for (int r = 0; r < 4; ++r) {
        const float p = exp2f((s[ct][r] - mrow[r]) * LOG2E);  // arg <= 0
        s[ct][r] = p;
        rsum[r] += p;
      }
#pragma unroll
    for (int x = 1; x < 16; x <<= 1)
#pragma unroll
      for (int r = 0; r < 4; ++r) rsum[r] += __shfl_xor(rsum[r], x, 64);
#pragma unroll
    for (int r = 0; r < 4; ++r) lsum[r] = lsum[r] * alpha[r] + rsum[r];
#pragma unroll
    for (int nt = 0; nt < 4; ++nt)
#pragma unroll
      for (int r = 0; r < 4; ++r) oacc[nt][r] *= alpha[r];

    // P (C-layout) -> wave-private LDS -> A-layout frags
#pragma unroll
    for (int ct = 0; ct < 4; ++ct)
#pragma unroll
      for (int r = 0; r < 4; ++r)
        myP[(qd * 4 + r) * SK + ct * 16 + lr] = f2b(s[ct][r]);

    bf16x8 pa[2];
#pragma unroll
    for (int kc = 0; kc < 2; ++kc)
      pa[kc] = ldb8(&myP[lr * SK + (kc * 4 + qd) * 8]);
#pragma unroll
    for (int nt = 0; nt < 4; ++nt) {
      const int rv = nt * 16 + lr;
#pragma unroll
      for (int kc = 0; kc < 2; ++kc) {
        const bf16x8 bv = ldb8(&shV[rv * SK + (kc * 4 + qd) * 8]);
        oacc[nt] = __builtin_amdgcn_mfma_f32_16x16x32_bf16(pa[kc], bv, oacc[nt], 0, 0, 0);
      }
    }
    __syncthreads();
  }

  const int b = bh >> 4, h = bh & 15;
#pragma unroll
  for (int nt = 0; nt < 4; ++nt)
#pragma unroll
    for (int r = 0; r < 4; ++r) {
      const int trow = q0 + w * 16 + qd * 4 + r;
      const int col = h * 64 + nt * 16 + lr;
      AO[((size_t)b * Tn + trow) * En + col] = f2b(oacc[nt][r] / lsum[r]);
    }
}

extern "C" void kernel_launch(void* const* d_in, const int* in_sizes, int n_in,
                              void* d_out, int out_size, void* d_ws, size_t ws_size,
                              hipStream_t stream) {
  (void)in_sizes; (void)n_in; (void)out_size; (void)ws_size;
  const float* x = (const float*)d_in[0];      // [2,2048,1024] f32
  const float* wqkv = (const float*)d_in[1];   // [3072,1024]  f32
  const float* wout = (const float*)d_in[2];   // [1024,1024]  f32
  float* out = (float*)d_out;                  // [2,2048,1024] f32

  const size_t elems = (size_t)Bn * Hn * Tn * Dn;  // 4M elements = 8 MiB bf16
  unsigned short* Qh = (unsigned short*)d_ws;
  unsigned short* Ql = Qh + elems;
  unsigned short* Kh = Ql + elems;
  unsigned short* Kl = Kh + elems;
  unsigned short* Vb = Kl + elems;
  unsigned short* AOb = Vb + elems;
  unsigned short* wh = AOb + elems;            // +6 MiB
  unsigned short* wl = wh + (size_t)3 * En * En;  // +6 MiB (total ws 60 MiB)

  // d_out (16 MiB) doubles as scratch for the x hi/lo split; fully
  // overwritten by gemm_out at the end.
  unsigned short* xh = (unsigned short*)d_out;
  unsigned short* xl = xh + elems;

  const int M = Bn * Tn;  // 4096
  dim3 blk(256);
  split_f32_bf16<<<dim3((int)(elems / 1024)), blk, 0, stream>>>(x, xh, xl);
  split_f32_bf16<<<dim3(3 * En * En / 1024), blk, 0, stream>>>(wqkv, wh, wl);
  gemm_qkv_split<<<dim3(24, M / 128), blk, 0, stream>>>(
      xh, xl, wh, wl, Qh, Ql, Kh, Kl, Vb, M, En);
  attn_kernel<<<dim3(Tn / 64, Bn * Hn), blk, 0, stream>>>(Qh, Ql, Kh, Kl, Vb, AOb);
  gemm_out<<<dim3(En / 128, M / 128), blk, 0, stream>>>(
      AOb, wout, out, M, En, En);
}

// Round 11
// 332.847 us; speedup vs baseline: 1.6544x; 1.2203x over previous
//
#include <hip/hip_runtime.h>
#include <hip/hip_bf16.h>

typedef __bf16 bf16x8 __attribute__((ext_vector_type(8)));
typedef _Float16 f16x8 __attribute__((ext_vector_type(8)));
typedef unsigned short u16x8 __attribute__((ext_vector_type(8)));
typedef float f32x4 __attribute__((ext_vector_type(4)));

static constexpr int Bn = 2;
static constexpr int Tn = 2048;
static constexpr int En = 1024;
static constexpr int Hn = 16;
static constexpr int Dn = 64;
#define LOG2E 1.44269504088896340736f

static constexpr int SK = 72;   // P-buffer stride (144B rows, 16B-aligned)
static constexpr int TS = 136;  // epilogue transpose stride (272B rows)

__device__ __forceinline__ unsigned short f2b(float x) {
  __hip_bfloat16 h = __float2bfloat16(x);
  return __builtin_bit_cast(unsigned short, h);
}
__device__ __forceinline__ float b2f(unsigned short u) {
  return __builtin_bit_cast(float, (unsigned)u << 16);
}
__device__ __forceinline__ unsigned short f2h(float x) {
  _Float16 h = (_Float16)x;
  return __builtin_bit_cast(unsigned short, h);
}
__device__ __forceinline__ bf16x8 ldb8(const unsigned short* p) {
  return __builtin_bit_cast(bf16x8, *reinterpret_cast<const u16x8*>(p));
}
__device__ __forceinline__ f16x8 ldh8(const unsigned short* p) {
  return __builtin_bit_cast(f16x8, *reinterpret_cast<const u16x8*>(p));
}
// async global->LDS, 16B/lane; LDS dest must be wave-uniform base (+lane*16)
__device__ __forceinline__ void gld16(const void* g, void* l) {
  __builtin_amdgcn_global_load_lds(
      (__attribute__((address_space(1))) void*)(const_cast<void*>(g)),
      (__attribute__((address_space(3))) void*)(l), 16, 0, 0);
}

// hi/lo bf16 split of f32 array (hoisted out of GEMM k-loop)
__global__ __launch_bounds__(256) void split_f32_bf16(
    const float* __restrict__ src, unsigned short* __restrict__ hi,
    unsigned short* __restrict__ lo)
{
  const int i = (blockIdx.x * 256 + threadIdx.x) * 4;
  const float4 v = *reinterpret_cast<const float4*>(src + i);
  ushort4 h, l;
  h.x = f2b(v.x); l.x = f2b(v.x - b2f(h.x));
  h.y = f2b(v.y); l.y = f2b(v.y - b2f(h.y));
  h.z = f2b(v.z); l.z = f2b(v.z - b2f(h.z));
  h.w = f2b(v.w); l.w = f2b(v.w - b2f(h.w));
  *reinterpret_cast<ushort4*>(hi + i) = h;
  *reinterpret_cast<ushort4*>(lo + i) = l;
}

// f32 -> bf16 cast (for wout, so gemm_out staging is a pure copy)
__global__ __launch_bounds__(256) void cvt_f32_bf16(
    const float* __restrict__ src, unsigned short* __restrict__ dst)
{
  const int i = (blockIdx.x * 256 + threadIdx.x) * 4;
  const float4 v = *reinterpret_cast<const float4*>(src + i);
  ushort4 u;
  u.x = f2b(v.x); u.y = f2b(v.y); u.z = f2b(v.z); u.w = f2b(v.w);
  *reinterpret_cast<ushort4*>(dst + i) = u;
}

// QKV GEMM, dbf16 compute (3 MFMA; V-blocks: 1), gld16 staging, permuted
// column tiling c' = kk*1024 + hh*64 + dd (w_qkv row n = dd*48+kk*16+hh).
// Outputs fp16: Q (x8), K [b,h,t,d]; V [b,h,d,t].
__global__ __launch_bounds__(256) void gemm_qkv_split(
    const unsigned short* __restrict__ xh, const unsigned short* __restrict__ xl,
    const unsigned short* __restrict__ wh, const unsigned short* __restrict__ wl,
    unsigned short* __restrict__ Qf, unsigned short* __restrict__ Kf,
    unsigned short* __restrict__ Vf, int M, int K)
{
  __shared__ unsigned short smem[128 * TS];  // 34816 B; staging uses 32 KB
  unsigned short* shAh = smem;               // 128x32 each, unpadded 64B rows
  unsigned short* shAl = smem + 4096;
  unsigned short* shBh = smem + 8192;
  unsigned short* shBl = smem + 12288;

  const int tid = threadIdx.x;
  const int w = tid >> 6;
  const int L = tid & 63;
  const int qd = L >> 4;
  const int lr = L & 15;
  const int m0 = blockIdx.y * 128;
  const int kk = blockIdx.x >> 3;          // 0=Q 1=K 2=V (uniform per block)
  const int hh0 = (blockIdx.x & 7) * 2;    // two heads per block
  const int wm = (w >> 1) * 64;
  const int wn = (w & 1) * 64;

  f32x4 acc[4][4] = {};

  for (int k0 = 0; k0 < K; k0 += 32) {
#pragma unroll
    for (int p = 0; p < 2; ++p) {
      const int c = p * 256 + tid;           // 512 16B-chunks per tile
      const int row = c >> 2, slot = c & 3;
      const int dd = row & 63, hl = row >> 6;
      const int nB = dd * 48 + kk * 16 + hh0 + hl;
      const size_t aoff = (size_t)(m0 + row) * K + k0 + slot * 8;
      const size_t boff = (size_t)nB * K + k0 + slot * 8;
      const int base = (p * 4 + w) * 512;    // wave-uniform LDS base (shorts)
      gld16(xh + aoff, &shAh[base]);
      gld16(wh + boff, &shBh[base]);
      if (kk < 2) {
        gld16(xl + aoff, &shAl[base]);
        gld16(wl + boff, &shBl[base]);
      }
    }
    __syncthreads();

    bf16x8 afh[4], bfh[4];
#pragma unroll
    for (int mt = 0; mt < 4; ++mt)
      afh[mt] = ldb8(&shAh[(wm + mt * 16 + lr) * 32 + qd * 8]);
#pragma unroll
    for (int nt = 0; nt < 4; ++nt)
      bfh[nt] = ldb8(&shBh[(wn + nt * 16 + lr) * 32 + qd * 8]);
    if (kk < 2) {
      bf16x8 afl[4], bfl[4];
#pragma unroll
      for (int mt = 0; mt < 4; ++mt)
        afl[mt] = ldb8(&shAl[(wm + mt * 16 + lr) * 32 + qd * 8]);
#pragma unroll
      for (int nt = 0; nt < 4; ++nt)
        bfl[nt] = ldb8(&shBl[(wn + nt * 16 + lr) * 32 + qd * 8]);
#pragma unroll
      for (int mt = 0; mt < 4; ++mt)
#pragma unroll
        for (int nt = 0; nt < 4; ++nt) {
          acc[mt][nt] = __builtin_amdgcn_mfma_f32_16x16x32_bf16(afh[mt], bfh[nt], acc[mt][nt], 0, 0, 0);
          acc[mt][nt] = __builtin_amdgcn_mfma_f32_16x16x32_bf16(afh[mt], bfl[nt], acc[mt][nt], 0, 0, 0);
          acc[mt][nt] = __builtin_amdgcn_mfma_f32_16x16x32_bf16(afl[mt], bfh[nt], acc[mt][nt], 0, 0, 0);
        }
    } else {
#pragma unroll
      for (int mt = 0; mt < 4; ++mt)
#pragma unroll
        for (int nt = 0; nt < 4; ++nt)
          acc[mt][nt] = __builtin_amdgcn_mfma_f32_16x16x32_bf16(afh[mt], bfh[nt], acc[mt][nt], 0, 0, 0);
    }
    __syncthreads();
  }

  // epilogue: fp16 into LDS transpose buffer -> coalesced 16B stores
  const int b = m0 >> 11;
  const int t0 = m0 & (Tn - 1);
  const float qscale = (kk == 0) ? 8.0f : 1.0f;  // fold *sqrt(d) into Q
#pragma unroll
  for (int mt = 0; mt < 4; ++mt)
#pragma unroll
    for (int nt = 0; nt < 4; ++nt)
#pragma unroll
      for (int r = 0; r < 4; ++r) {
        const int ml = wm + mt * 16 + qd * 4 + r;  // C/D row=(lane>>4)*4+reg
        const int cl = wn + nt * 16 + lr;          // C/D col=lane&15
        smem[ml * TS + cl] = f2h(acc[mt][nt][r] * qscale);
      }
  __syncthreads();

  unsigned short* dst = (kk == 0) ? Qf : (kk == 1) ? Kf : Vf;
  if (kk < 2) {
    // Q/K [b,h,t,d]: contiguous along dd
#pragma unroll
    for (int p = 0; p < 8; ++p) {
      const int s = p * 256 + tid;
      const int tl = s >> 4, sub = s & 15;
      const int hl = sub >> 3, oct = sub & 7;
      const u16x8 v = *reinterpret_cast<const u16x8*>(&smem[tl * TS + hl * 64 + oct * 8]);
      *reinterpret_cast<u16x8*>(
          dst + ((size_t)(b * Hn + hh0 + hl) * Tn + t0 + tl) * Dn + oct * 8) = v;
    }
  } else {
    // V [b,h,d,t]: contiguous along t (column gather from LDS)
#pragma unroll
    for (int p = 0; p < 8; ++p) {
      const int s = p * 256 + tid;
      const int cl = s >> 4, oct = s & 15;
      const int hl = cl >> 6, dd = cl & 63;
      u16x8 v;
#pragma unroll
      for (int j = 0; j < 8; ++j) v[j] = smem[(oct * 8 + j) * TS + cl];
      *reinterpret_cast<u16x8*>(
          dst + ((size_t)((b * Hn + hh0 + hl) * Dn + dd)) * Tn + t0 + oct * 8) = v;
    }
  }
}

// Flash attention, fp16 energy (single MFMA), gld16 staging.
// Qf (x8), Kf: fp16 [b,h,t,d]  Vf: fp16 [b,h,d,t]  AO: bf16 [b,t,(h d)]
// K/V LDS layout: [kc][64 rows][32] subtiles (64B rows, gld16-compatible).
__global__ __launch_bounds__(256) void attn_kernel(
    const unsigned short* __restrict__ Qf, const unsigned short* __restrict__ Kf,
    const unsigned short* __restrict__ Vf, unsigned short* __restrict__ AO)
{
  __shared__ unsigned short shK[2 * 64 * 32];   // 8 KB
  __shared__ unsigned short shV[2 * 64 * 32];   // 8 KB
  __shared__ unsigned short shP[4 * 16 * SK];   // 9.2 KB (padded, scalar writes)
  const int tid = threadIdx.x;
  const int w = tid >> 6;
  const int L = tid & 63;
  const int qd = L >> 4;
  const int lr = L & 15;
  const int q0 = blockIdx.x * 64;
  const int bh = blockIdx.y;
  unsigned short* myP = &shP[w * 16 * SK];

  f16x8 aq[2];
  {
    const size_t qoff = ((size_t)bh * Tn + q0 + w * 16 + lr) * Dn;
    aq[0] = ldh8(Qf + qoff + qd * 8);
    aq[1] = ldh8(Qf + qoff + 32 + qd * 8);
  }

  f32x4 oacc[4] = {};
  float mrow[4] = {-1e30f, -1e30f, -1e30f, -1e30f};
  float lsum[4] = {0.f, 0.f, 0.f, 0.f};

  for (int j0 = 0; j0 < Tn; j0 += 64) {
#pragma unroll
    for (int p = 0; p < 2; ++p) {
      const int c = p * 256 + tid;             // 512 chunks per tile; kc == p
      const int row = (c >> 2) & 63, slot = c & 3;
      const int base = (p * 4 + w) * 512;      // wave-uniform LDS base
      gld16(Kf + ((size_t)bh * Tn + j0 + row) * Dn + p * 32 + slot * 8, &shK[base]);
      gld16(Vf + ((size_t)bh * Dn + row) * Tn + j0 + p * 32 + slot * 8, &shV[base]);
    }
    __syncthreads();

    // S = Q K^T (Q pre-scaled by 8) — single fp16 MFMA per frag pair
    f32x4 s[4] = {};
#pragma unroll
    for (int ct = 0; ct < 4; ++ct) {
      const int rk = ct * 16 + lr;
#pragma unroll
      for (int kc = 0; kc < 2; ++kc) {
        const f16x8 bk = ldh8(&shK[kc * 2048 + rk * 32 + qd * 8]);
        s[ct] = __builtin_amdgcn_mfma_f32_16x16x32_f16(aq[kc], bk, s[ct], 0, 0, 0);
      }
    }

    // register softmax stats: row qd*4+r owned by this qd-group's 16 lanes
    float tmax[4];
#pragma unroll
    for (int r = 0; r < 4; ++r)
      tmax[r] = fmaxf(fmaxf(s[0][r], s[1][r]), fmaxf(s[2][r], s[3][r]));
#pragma unroll
    for (int x = 1; x < 16; x <<= 1)
#pragma unroll
      for (int r = 0; r < 4; ++r) tmax[r] = fmaxf(tmax[r], __shfl_xor(tmax[r], x, 64));

    float alpha[4], rsum[4];
#pragma unroll
    for (int r = 0; r < 4; ++r) {
      const float mn = fmaxf(mrow[r], tmax[r]);
      alpha[r] = exp2f((mrow[r] - mn) * LOG2E);
      mrow[r] = mn;
      rsum[r] = 0.f;
    }
#pragma unroll
    for (int ct = 0; ct < 4; ++ct)
#pragma unroll
      for (int r = 0; r < 4; ++r) {
        const float p = exp2f((s[ct][r] - mrow[r]) * LOG2E);  // arg <= 0
        s[ct][r] = p;
        rsum[r] += p;
      }
#pragma unroll
    for (int x = 1; x < 16; x <<= 1)
#pragma unroll
      for (int r = 0; r < 4; ++r) rsum[r] += __shfl_xor(rsum[r], x, 64);
#pragma unroll
    for (int r = 0; r < 4; ++r) lsum[r] = lsum[r] * alpha[r] + rsum[r];
#pragma unroll
    for (int nt = 0; nt < 4; ++nt)
#pragma unroll
      for (int r = 0; r < 4; ++r) oacc[nt][r] *= alpha[r];

    // P (C-layout) -> wave-private LDS (fp16) -> A-layout frags
#pragma unroll
    for (int ct = 0; ct < 4; ++ct)
#pragma unroll
      for (int r = 0; r < 4; ++r)
        myP[(qd * 4 + r) * SK + ct * 16 + lr] = f2h(s[ct][r]);

    f16x8 pa[2];
#pragma unroll
    for (int kc = 0; kc < 2; ++kc)
      pa[kc] = ldh8(&myP[lr * SK + kc * 32 + qd * 8]);
#pragma unroll
    for (int nt = 0; nt < 4; ++nt) {
      const int rv = nt * 16 + lr;
#pragma unroll
      for (int kc = 0; kc < 2; ++kc) {
        const f16x8 bv = ldh8(&shV[kc * 2048 + rv * 32 + qd * 8]);
        oacc[nt] = __builtin_amdgcn_mfma_f32_16x16x32_f16(pa[kc], bv, oacc[nt], 0, 0, 0);
      }
    }
    __syncthreads();
  }

  const int b = bh >> 4, h = bh & 15;
#pragma unroll
  for (int nt = 0; nt < 4; ++nt)
#pragma unroll
    for (int r = 0; r < 4; ++r) {
      const int trow = q0 + w * 16 + qd * 4 + r;
      const int col = h * 64 + nt * 16 + lr;
      AO[((size_t)b * Tn + trow) * En + col] = f2b(oacc[nt][r] / lsum[r]);
    }
}

// Out-projection (m97-shaped): OUT f32; A=AO bf16, B=wout bf16 (pre-cast).
__global__ __launch_bounds__(256) void gemm_out(
    const unsigned short* __restrict__ A, const unsigned short* __restrict__ Bm,
    float* __restrict__ C, int M, int N, int K)
{
  __shared__ unsigned short shA[128 * 32];
  __shared__ unsigned short shB[128 * 32];
  const int tid = threadIdx.x;
  const int w = tid >> 6;
  const int L = tid & 63;
  const int qd = L >> 4;
  const int lr = L & 15;
  const int m0 = blockIdx.y * 128;
  const int n0 = blockIdx.x * 128;
  const int wm = (w >> 1) * 64;
  const int wn = (w & 1) * 64;

  f32x4 acc[4][4] = {};

  for (int k0 = 0; k0 < K; k0 += 32) {
#pragma unroll
    for (int p = 0; p < 2; ++p) {
      const int c = p * 256 + tid;
      const int row = c >> 2, slot = c & 3;
      const int base = (p * 4 + w) * 512;
      gld16(A + (size_t)(m0 + row) * K + k0 + slot * 8, &shA[base]);
      gld16(Bm + (size_t)(n0 + row) * K + k0 + slot * 8, &shB[base]);
    }
    __syncthreads();

    bf16x8 af[4], bf[4];
#pragma unroll
    for (int mt = 0; mt < 4; ++mt)
      af[mt] = ldb8(&shA[(wm + mt * 16 + lr) * 32 + qd * 8]);
#pragma unroll
    for (int nt = 0; nt < 4; ++nt)
      bf[nt] = ldb8(&shB[(wn + nt * 16 + lr) * 32 + qd * 8]);
#pragma unroll
    for (int mt = 0; mt < 4; ++mt)
#pragma unroll
      for (int nt = 0; nt < 4; ++nt)
        acc[mt][nt] = __builtin_amdgcn_mfma_f32_16x16x32_bf16(af[mt], bf[nt], acc[mt][nt], 0, 0, 0);
    __syncthreads();
  }

#pragma unroll
  for (int mt = 0; mt < 4; ++mt)
#pragma unroll
    for (int nt = 0; nt < 4; ++nt)
#pragma unroll
      for (int r = 0; r < 4; ++r) {
        const int m = m0 + wm + mt * 16 + qd * 4 + r;
        const int n = n0 + wn + nt * 16 + lr;
        C[(size_t)m * N + n] = acc[mt][nt][r];
      }
}

extern "C" void kernel_launch(void* const* d_in, const int* in_sizes, int n_in,
                              void* d_out, int out_size, void* d_ws, size_t ws_size,
                              hipStream_t stream) {
  (void)in_sizes; (void)n_in; (void)out_size; (void)ws_size;
  const float* x = (const float*)d_in[0];      // [2,2048,1024] f32
  const float* wqkv = (const float*)d_in[1];   // [3072,1024]  f32
  const float* wout = (const float*)d_in[2];   // [1024,1024]  f32
  float* out = (float*)d_out;                  // [2,2048,1024] f32

  const size_t elems = (size_t)Bn * Hn * Tn * Dn;  // 4M elems (8 MiB @16-bit)
  unsigned short* Qf = (unsigned short*)d_ws;      // fp16
  unsigned short* Kf = Qf + elems;                 // fp16
  unsigned short* Vf = Kf + elems;                 // fp16
  unsigned short* AOb = Vf + elems;                // bf16
  unsigned short* wh = AOb + elems;                // bf16, 3M
  unsigned short* wl = wh + (size_t)3 * En * En;   // bf16, 3M
  unsigned short* wob = wl + (size_t)3 * En * En;  // bf16, 1M  (total 46 MiB)

  // d_out (16 MiB) doubles as scratch for x hi/lo; overwritten by gemm_out.
  unsigned short* xh = (unsigned short*)d_out;
  unsigned short* xl = xh + elems;

  const int M = Bn * Tn;  // 4096
  dim3 blk(256);
  split_f32_bf16<<<dim3((int)(elems / 1024)), blk, 0, stream>>>(x, xh, xl);
  split_f32_bf16<<<dim3(3 * En * En / 1024), blk, 0, stream>>>(wqkv, wh, wl);
  cvt_f32_bf16<<<dim3(En * En / 1024), blk, 0, stream>>>(wout, wob);
  gemm_qkv_split<<<dim3(24, M / 128), blk, 0, stream>>>(
      xh, xl, wh, wl, Qf, Kf, Vf, M, En);
  attn_kernel<<<dim3(Tn / 64, Bn * Hn), blk, 0, stream>>>(Qf, Kf, Vf, AOb);
  gemm_out<<<dim3(En / 128, M / 128), blk, 0, stream>>>(
      AOb, wob, out, M, En, En);
}

// Round 12
// 307.427 us; speedup vs baseline: 1.7912x; 1.0827x over previous
//
#include <hip/hip_runtime.h>
#include <hip/hip_bf16.h>

typedef _Float16 f16x8 __attribute__((ext_vector_type(8)));
typedef unsigned short u16x8 __attribute__((ext_vector_type(8)));
typedef float f32x4 __attribute__((ext_vector_type(4)));

static constexpr int Bn = 2;
static constexpr int Tn = 2048;
static constexpr int En = 1024;
static constexpr int Hn = 16;
static constexpr int Dn = 64;
#define LOG2E 1.44269504088896340736f

static constexpr int SP = 136;  // attn P-buffer stride (16 rows x 128 + pad)
static constexpr int TS = 136;  // qkv epilogue transpose stride

__device__ __forceinline__ unsigned short f2h(float x) {
  _Float16 h = (_Float16)x;
  return __builtin_bit_cast(unsigned short, h);
}
__device__ __forceinline__ float h2f(unsigned short u) {
  return (float)__builtin_bit_cast(_Float16, u);
}
__device__ __forceinline__ f16x8 ldh8(const unsigned short* p) {
  return __builtin_bit_cast(f16x8, *reinterpret_cast<const u16x8*>(p));
}
// async global->LDS, 16B/lane; LDS dest must be wave-uniform base (+lane*16)
__device__ __forceinline__ void gld16(const void* g, void* l) {
  __builtin_amdgcn_global_load_lds(
      (__attribute__((address_space(1))) void*)(const_cast<void*>(g)),
      (__attribute__((address_space(3))) void*)(l), 16, 0, 0);
}

// fp16 hi/lo split: (hi + lo) == x to ~22 mantissa bits
__global__ __launch_bounds__(256) void split_f32_f16(
    const float* __restrict__ src, unsigned short* __restrict__ hi,
    unsigned short* __restrict__ lo)
{
  const int i = (blockIdx.x * 256 + threadIdx.x) * 4;
  const float4 v = *reinterpret_cast<const float4*>(src + i);
  ushort4 h, l;
  h.x = f2h(v.x); l.x = f2h(v.x - h2f(h.x));
  h.y = f2h(v.y); l.y = f2h(v.y - h2f(h.y));
  h.z = f2h(v.z); l.z = f2h(v.z - h2f(h.z));
  h.w = f2h(v.w); l.w = f2h(v.w - h2f(h.w));
  *reinterpret_cast<ushort4*>(hi + i) = h;
  *reinterpret_cast<ushort4*>(lo + i) = l;
}

__global__ __launch_bounds__(256) void cvt_f32_f16(
    const float* __restrict__ src, unsigned short* __restrict__ dst)
{
  const int i = (blockIdx.x * 256 + threadIdx.x) * 4;
  const float4 v = *reinterpret_cast<const float4*>(src + i);
  ushort4 u;
  u.x = f2h(v.x); u.y = f2h(v.y); u.z = f2h(v.z); u.w = f2h(v.w);
  *reinterpret_cast<ushort4*>(dst + i) = u;
}

// QKV GEMM, fp16: A = x as fp16 hi+lo (exact), B = w_qkv fp16. Q/K: 2 MFMA,
// V: 1 MFMA. Permuted column tiling c' = kk*1024 + hh*64 + dd
// (w_qkv row n = dd*48+kk*16+hh). Outputs fp16: Q(x8),K [b,h,t,d]; V [b,h,d,t].
__global__ __launch_bounds__(256) void gemm_qkv(
    const unsigned short* __restrict__ xh, const unsigned short* __restrict__ xl,
    const unsigned short* __restrict__ wf,
    unsigned short* __restrict__ Qf, unsigned short* __restrict__ Kf,
    unsigned short* __restrict__ Vf, int M, int K)
{
  __shared__ unsigned short smem[128 * TS];  // 34816 B; reused by epilogue
  unsigned short* shAh = smem;               // 128x32 each, unpadded
  unsigned short* shAl = smem + 4096;
  unsigned short* shB = smem + 8192;

  const int tid = threadIdx.x;
  const int w = tid >> 6, L = tid & 63, qd = L >> 4, lr = L & 15;
  const int m0 = blockIdx.y * 128;
  const int kk = blockIdx.x >> 3;          // 0=Q 1=K 2=V (uniform per block)
  const int hh0 = (blockIdx.x & 7) * 2;    // two heads per block
  const int wm = (w >> 1) * 64, wn = (w & 1) * 64;

  f32x4 acc[4][4] = {};

  for (int k0 = 0; k0 < K; k0 += 32) {
#pragma unroll
    for (int p = 0; p < 2; ++p) {
      const int c = p * 256 + tid;
      const int row = c >> 2, slot = c & 3;
      const int dd = row & 63, hl = row >> 6;
      const int nB = dd * 48 + kk * 16 + hh0 + hl;
      const size_t aoff = (size_t)(m0 + row) * K + k0 + slot * 8;
      const size_t boff = (size_t)nB * K + k0 + slot * 8;
      const int base = (p * 4 + w) * 512;  // wave-uniform LDS base (shorts)
      gld16(xh + aoff, &shAh[base]);
      gld16(wf + boff, &shB[base]);
      if (kk < 2) gld16(xl + aoff, &shAl[base]);
    }
    __syncthreads();

    f16x8 afh[4], bf[4];
#pragma unroll
    for (int mt = 0; mt < 4; ++mt)
      afh[mt] = ldh8(&shAh[(wm + mt * 16 + lr) * 32 + qd * 8]);
#pragma unroll
    for (int nt = 0; nt < 4; ++nt)
      bf[nt] = ldh8(&shB[(wn + nt * 16 + lr) * 32 + qd * 8]);
    if (kk < 2) {
      f16x8 afl[4];
#pragma unroll
      for (int mt = 0; mt < 4; ++mt)
        afl[mt] = ldh8(&shAl[(wm + mt * 16 + lr) * 32 + qd * 8]);
#pragma unroll
      for (int mt = 0; mt < 4; ++mt)
#pragma unroll
        for (int nt = 0; nt < 4; ++nt) {
          acc[mt][nt] = __builtin_amdgcn_mfma_f32_16x16x32_f16(afh[mt], bf[nt], acc[mt][nt], 0, 0, 0);
          acc[mt][nt] = __builtin_amdgcn_mfma_f32_16x16x32_f16(afl[mt], bf[nt], acc[mt][nt], 0, 0, 0);
        }
    } else {
#pragma unroll
      for (int mt = 0; mt < 4; ++mt)
#pragma unroll
        for (int nt = 0; nt < 4; ++nt)
          acc[mt][nt] = __builtin_amdgcn_mfma_f32_16x16x32_f16(afh[mt], bf[nt], acc[mt][nt], 0, 0, 0);
    }
    __syncthreads();
  }

  // epilogue: fp16 into LDS transpose buffer -> coalesced 16B stores
  const int b = m0 >> 11;
  const int t0 = m0 & (Tn - 1);
  const float qscale = (kk == 0) ? 8.0f : 1.0f;  // fold *sqrt(d) into Q
#pragma unroll
  for (int mt = 0; mt < 4; ++mt)
#pragma unroll
    for (int nt = 0; nt < 4; ++nt)
#pragma unroll
      for (int r = 0; r < 4; ++r) {
        const int ml = wm + mt * 16 + qd * 4 + r;  // C/D row=(lane>>4)*4+reg
        const int cl = wn + nt * 16 + lr;          // C/D col=lane&15
        smem[ml * TS + cl] = f2h(acc[mt][nt][r] * qscale);
      }
  __syncthreads();

  unsigned short* dst = (kk == 0) ? Qf : (kk == 1) ? Kf : Vf;
  if (kk < 2) {
#pragma unroll
    for (int p = 0; p < 8; ++p) {
      const int s = p * 256 + tid;
      const int tl = s >> 4, sub = s & 15;
      const int hl = sub >> 3, oct = sub & 7;
      const u16x8 v = *reinterpret_cast<const u16x8*>(&smem[tl * TS + hl * 64 + oct * 8]);
      *reinterpret_cast<u16x8*>(
          dst + ((size_t)(b * Hn + hh0 + hl) * Tn + t0 + tl) * Dn + oct * 8) = v;
    }
  } else {
#pragma unroll
    for (int p = 0; p < 8; ++p) {
      const int s = p * 256 + tid;
      const int cl = s >> 4, oct = s & 15;
      const int hl = cl >> 6, dd = cl & 63;
      u16x8 v;
#pragma unroll
      for (int j = 0; j < 8; ++j) v[j] = smem[(oct * 8 + j) * TS + cl];
      *reinterpret_cast<u16x8*>(
          dst + ((size_t)((b * Hn + hh0 + hl) * Dn + dd)) * Tn + t0 + oct * 8) = v;
    }
  }
}

// Flash attention, fp16 energy, j-tile = 128 (merged reductions, half the
// barriers/shfl per element). Qf(x8),Kf: [b,h,t,d]  Vf: [b,h,d,t]  AO: fp16.
__global__ __launch_bounds__(256) void attn_kernel(
    const unsigned short* __restrict__ Qf, const unsigned short* __restrict__ Kf,
    const unsigned short* __restrict__ Vf, unsigned short* __restrict__ AOf)
{
  __shared__ unsigned short shK[2 * 128 * 32];  // [kc][j row][32]  16 KB
  __shared__ unsigned short shV[4 * 64 * 32];   // [kcv][dd][32]    16 KB
  __shared__ unsigned short shP[4 * 16 * SP];   // per-wave 16x128  17 KB
  const int tid = threadIdx.x;
  const int w = tid >> 6, L = tid & 63, qd = L >> 4, lr = L & 15;
  const int q0 = blockIdx.x * 64;
  const int bh = blockIdx.y;
  unsigned short* myP = &shP[w * 16 * SP];

  f16x8 aq[2];
  {
    const size_t qoff = ((size_t)bh * Tn + q0 + w * 16 + lr) * Dn;
    aq[0] = ldh8(Qf + qoff + qd * 8);
    aq[1] = ldh8(Qf + qoff + 32 + qd * 8);
  }

  f32x4 oacc[4] = {};
  float mrow[4] = {-1e30f, -1e30f, -1e30f, -1e30f};
  float lsum[4] = {0.f, 0.f, 0.f, 0.f};

  for (int j0 = 0; j0 < Tn; j0 += 128) {
    // stage K tile (128 j x 64 d) as [kc][row][32]
#pragma unroll
    for (int p = 0; p < 4; ++p) {
      const int kc = p >> 1, half = p & 1;
      const int row = half * 64 + (tid >> 2);   // lane: row=half*64+w*16+(L>>2)
      const int slot = tid & 3;
      gld16(Kf + ((size_t)bh * Tn + j0 + row) * Dn + kc * 32 + slot * 8,
            &shK[kc * 4096 + (half * 64 + w * 16) * 32]);
    }
    // stage V tile (64 d x 128 t) as [kcv][dd][32]
#pragma unroll
    for (int p = 0; p < 4; ++p) {
      const int dd = tid >> 2, slot = tid & 3;
      gld16(Vf + ((size_t)bh * Dn + dd) * Tn + j0 + p * 32 + slot * 8,
            &shV[p * 2048 + (w * 16) * 32]);
    }
    __syncthreads();

    // S = Q K^T (Q pre-scaled by 8): 8 col-blocks of 16
    f32x4 s[8];
#pragma unroll
    for (int ct = 0; ct < 8; ++ct) {
      s[ct] = f32x4{0.f, 0.f, 0.f, 0.f};
      const int rk = ct * 16 + lr;
#pragma unroll
      for (int kc = 0; kc < 2; ++kc) {
        const f16x8 bk = ldh8(&shK[kc * 4096 + rk * 32 + qd * 8]);
        s[ct] = __builtin_amdgcn_mfma_f32_16x16x32_f16(aq[kc], bk, s[ct], 0, 0, 0);
      }
    }

    // merged online softmax over all 128 cols
    float tmax[4];
#pragma unroll
    for (int r = 0; r < 4; ++r) {
      tmax[r] = s[0][r];
#pragma unroll
      for (int ct = 1; ct < 8; ++ct) tmax[r] = fmaxf(tmax[r], s[ct][r]);
    }
#pragma unroll
    for (int x = 1; x < 16; x <<= 1)
#pragma unroll
      for (int r = 0; r < 4; ++r) tmax[r] = fmaxf(tmax[r], __shfl_xor(tmax[r], x, 64));

    float alpha[4], rsum[4];
#pragma unroll
    for (int r = 0; r < 4; ++r) {
      const float mn = fmaxf(mrow[r], tmax[r]);
      alpha[r] = exp2f((mrow[r] - mn) * LOG2E);
      mrow[r] = mn;
      rsum[r] = 0.f;
    }
#pragma unroll
    for (int ct = 0; ct < 8; ++ct)
#pragma unroll
      for (int r = 0; r < 4; ++r) {
        const float p = exp2f((s[ct][r] - mrow[r]) * LOG2E);  // arg <= 0
        s[ct][r] = p;
        rsum[r] += p;
      }
#pragma unroll
    for (int x = 1; x < 16; x <<= 1)
#pragma unroll
      for (int r = 0; r < 4; ++r) rsum[r] += __shfl_xor(rsum[r], x, 64);
#pragma unroll
    for (int r = 0; r < 4; ++r) lsum[r] = lsum[r] * alpha[r] + rsum[r];
#pragma unroll
    for (int nt = 0; nt < 4; ++nt)
#pragma unroll
      for (int r = 0; r < 4; ++r) oacc[nt][r] *= alpha[r];

    // P (C-layout) -> wave-private LDS -> A-layout frags (no barrier needed)
#pragma unroll
    for (int ct = 0; ct < 8; ++ct)
#pragma unroll
      for (int r = 0; r < 4; ++r)
        myP[(qd * 4 + r) * SP + ct * 16 + lr] = f2h(s[ct][r]);

    f16x8 pa[4];
#pragma unroll
    for (int kcv = 0; kcv < 4; ++kcv)
      pa[kcv] = ldh8(&myP[lr * SP + kcv * 32 + qd * 8]);
#pragma unroll
    for (int nt = 0; nt < 4; ++nt) {
      const int rv = nt * 16 + lr;
#pragma unroll
      for (int kcv = 0; kcv < 4; ++kcv) {
        const f16x8 bv = ldh8(&shV[kcv * 2048 + rv * 32 + qd * 8]);
        oacc[nt] = __builtin_amdgcn_mfma_f32_16x16x32_f16(pa[kcv], bv, oacc[nt], 0, 0, 0);
      }
    }
    __syncthreads();
  }

  const int b = bh >> 4, h = bh & 15;
#pragma unroll
  for (int nt = 0; nt < 4; ++nt)
#pragma unroll
    for (int r = 0; r < 4; ++r) {
      const int trow = q0 + w * 16 + qd * 4 + r;
      const int col = h * 64 + nt * 16 + lr;
      AOf[((size_t)b * Tn + trow) * En + col] = f2h(oacc[nt][r] / lsum[r]);
    }
}

// Out-projection: OUT f32; A = AO fp16, B = wout fp16 (pre-cast).
__global__ __launch_bounds__(256) void gemm_out(
    const unsigned short* __restrict__ A, const unsigned short* __restrict__ Bm,
    float* __restrict__ C, int M, int N, int K)
{
  __shared__ unsigned short shA[128 * 32];
  __shared__ unsigned short shB[128 * 32];
  const int tid = threadIdx.x;
  const int w = tid >> 6, L = tid & 63, qd = L >> 4, lr = L & 15;
  const int m0 = blockIdx.y * 128;
  const int n0 = blockIdx.x * 128;
  const int wm = (w >> 1) * 64, wn = (w & 1) * 64;

  f32x4 acc[4][4] = {};

  for (int k0 = 0; k0 < K; k0 += 32) {
#pragma unroll
    for (int p = 0; p < 2; ++p) {
      const int c = p * 256 + tid;
      const int row = c >> 2, slot = c & 3;
      const int base = (p * 4 + w) * 512;
      gld16(A + (size_t)(m0 + row) * K + k0 + slot * 8, &shA[base]);
      gld16(Bm + (size_t)(n0 + row) * K + k0 + slot * 8, &shB[base]);
    }
    __syncthreads();

    f16x8 af[4], bf[4];
#pragma unroll
    for (int mt = 0; mt < 4; ++mt)
      af[mt] = ldh8(&shA[(wm + mt * 16 + lr) * 32 + qd * 8]);
#pragma unroll
    for (int nt = 0; nt < 4; ++nt)
      bf[nt] = ldh8(&shB[(wn + nt * 16 + lr) * 32 + qd * 8]);
#pragma unroll
    for (int mt = 0; mt < 4; ++mt)
#pragma unroll
      for (int nt = 0; nt < 4; ++nt)
        acc[mt][nt] = __builtin_amdgcn_mfma_f32_16x16x32_f16(af[mt], bf[nt], acc[mt][nt], 0, 0, 0);
    __syncthreads();
  }

#pragma unroll
  for (int mt = 0; mt < 4; ++mt)
#pragma unroll
    for (int nt = 0; nt < 4; ++nt)
#pragma unroll
      for (int r = 0; r < 4; ++r) {
        const int m = m0 + wm + mt * 16 + qd * 4 + r;
        const int n = n0 + wn + nt * 16 + lr;
        C[(size_t)m * N + n] = acc[mt][nt][r];
      }
}

extern "C" void kernel_launch(void* const* d_in, const int* in_sizes, int n_in,
                              void* d_out, int out_size, void* d_ws, size_t ws_size,
                              hipStream_t stream) {
  (void)in_sizes; (void)n_in; (void)out_size; (void)ws_size;
  const float* x = (const float*)d_in[0];      // [2,2048,1024] f32
  const float* wqkv = (const float*)d_in[1];   // [3072,1024]  f32
  const float* wout = (const float*)d_in[2];   // [1024,1024]  f32
  float* out = (float*)d_out;                  // [2,2048,1024] f32

  const size_t elems = (size_t)Bn * Hn * Tn * Dn;  // 4M elems (8 MiB fp16)
  unsigned short* Qf = (unsigned short*)d_ws;
  unsigned short* Kf = Qf + elems;
  unsigned short* Vf = Kf + elems;
  unsigned short* AOf = Vf + elems;
  unsigned short* wf = AOf + elems;                // fp16 w_qkv, 3M
  unsigned short* wof = wf + (size_t)3 * En * En;  // fp16 wout, 1M (40 MiB)

  // d_out (16 MiB) doubles as scratch for x hi/lo; overwritten by gemm_out.
  unsigned short* xh = (unsigned short*)d_out;
  unsigned short* xl = xh + elems;

  const int M = Bn * Tn;  // 4096
  dim3 blk(256);
  split_f32_f16<<<dim3((int)(elems / 1024)), blk, 0, stream>>>(x, xh, xl);
  cvt_f32_f16<<<dim3(3 * En * En / 1024), blk, 0, stream>>>(wqkv, wf);
  cvt_f32_f16<<<dim3(En * En / 1024), blk, 0, stream>>>(wout, wof);
  gemm_qkv<<<dim3(24, M / 128), blk, 0, stream>>>(
      xh, xl, wf, Qf, Kf, Vf, M, En);
  attn_kernel<<<dim3(Tn / 64, Bn * Hn), blk, 0, stream>>>(Qf, Kf, Vf, AOf);
  gemm_out<<<dim3(En / 128, M / 128), blk, 0, stream>>>(
      AOf, wof, out, M, En, En);
}

// Round 13
// 276.329 us; speedup vs baseline: 1.9928x; 1.1125x over previous
//
#include <hip/hip_runtime.h>
#include <hip/hip_bf16.h>

typedef _Float16 f16x8 __attribute__((ext_vector_type(8)));
typedef unsigned short u16x8 __attribute__((ext_vector_type(8)));
typedef float f32x4 __attribute__((ext_vector_type(4)));

static constexpr int Bn = 2;
static constexpr int Tn = 2048;
static constexpr int En = 1024;
static constexpr int Hn = 16;
static constexpr int Dn = 64;
#define LOG2E 1.44269504088896340736f

static constexpr int TS = 136;  // qkv epilogue transpose stride
static constexpr int PS = 40;   // attn P-chunk row stride (shorts): 20 dwords
                                // -> 16-lane b128 reads land 2-way (free, m136)

__device__ __forceinline__ unsigned short f2h(float x) {
  _Float16 h = (_Float16)x;
  return __builtin_bit_cast(unsigned short, h);
}
__device__ __forceinline__ float h2f(unsigned short u) {
  return (float)__builtin_bit_cast(_Float16, u);
}
__device__ __forceinline__ f16x8 ldh8(const unsigned short* p) {
  return __builtin_bit_cast(f16x8, *reinterpret_cast<const u16x8*>(p));
}
// async global->LDS, 16B/lane; LDS dest must be wave-uniform base (+lane*16)
__device__ __forceinline__ void gld16(const void* g, void* l) {
  __builtin_amdgcn_global_load_lds(
      (__attribute__((address_space(1))) void*)(const_cast<void*>(g)),
      (__attribute__((address_space(3))) void*)(l), 16, 0, 0);
}

// fp16 hi/lo split: (hi + lo) == x to ~22 mantissa bits
__global__ __launch_bounds__(256) void split_f32_f16(
    const float* __restrict__ src, unsigned short* __restrict__ hi,
    unsigned short* __restrict__ lo)
{
  const int i = (blockIdx.x * 256 + threadIdx.x) * 4;
  const float4 v = *reinterpret_cast<const float4*>(src + i);
  ushort4 h, l;
  h.x = f2h(v.x); l.x = f2h(v.x - h2f(h.x));
  h.y = f2h(v.y); l.y = f2h(v.y - h2f(h.y));
  h.z = f2h(v.z); l.z = f2h(v.z - h2f(h.z));
  h.w = f2h(v.w); l.w = f2h(v.w - h2f(h.w));
  *reinterpret_cast<ushort4*>(hi + i) = h;
  *reinterpret_cast<ushort4*>(lo + i) = l;
}

__global__ __launch_bounds__(256) void cvt_f32_f16(
    const float* __restrict__ src, unsigned short* __restrict__ dst)
{
  const int i = (blockIdx.x * 256 + threadIdx.x) * 4;
  const float4 v = *reinterpret_cast<const float4*>(src + i);
  ushort4 u;
  u.x = f2h(v.x); u.y = f2h(v.y); u.z = f2h(v.z); u.w = f2h(v.w);
  *reinterpret_cast<ushort4*>(dst + i) = u;
}

// QKV GEMM, fp16: A = x as fp16 hi+lo (exact), B = w_qkv fp16. Q/K: 2 MFMA,
// V: 1 MFMA. Permuted column tiling c' = kk*1024 + hh*64 + dd
// (w_qkv row n = dd*48+kk*16+hh). Outputs fp16: Q(x8),K [b,h,t,d]; V [b,h,d,t].
__global__ __launch_bounds__(256) void gemm_qkv(
    const unsigned short* __restrict__ xh, const unsigned short* __restrict__ xl,
    const unsigned short* __restrict__ wf,
    unsigned short* __restrict__ Qf, unsigned short* __restrict__ Kf,
    unsigned short* __restrict__ Vf, int M, int K)
{
  __shared__ unsigned short smem[128 * TS];  // 34816 B; reused by epilogue
  unsigned short* shAh = smem;               // 128x32 each, unpadded
  unsigned short* shAl = smem + 4096;
  unsigned short* shB = smem + 8192;

  const int tid = threadIdx.x;
  const int w = tid >> 6, L = tid & 63, qd = L >> 4, lr = L & 15;
  const int m0 = blockIdx.y * 128;
  const int kk = blockIdx.x >> 3;          // 0=Q 1=K 2=V (uniform per block)
  const int hh0 = (blockIdx.x & 7) * 2;    // two heads per block
  const int wm = (w >> 1) * 64, wn = (w & 1) * 64;

  f32x4 acc[4][4] = {};

  for (int k0 = 0; k0 < K; k0 += 32) {
#pragma unroll
    for (int p = 0; p < 2; ++p) {
      const int c = p * 256 + tid;
      const int row = c >> 2, slot = c & 3;
      const int dd = row & 63, hl = row >> 6;
      const int nB = dd * 48 + kk * 16 + hh0 + hl;
      const size_t aoff = (size_t)(m0 + row) * K + k0 + slot * 8;
      const size_t boff = (size_t)nB * K + k0 + slot * 8;
      const int base = (p * 4 + w) * 512;  // wave-uniform LDS base (shorts)
      gld16(xh + aoff, &shAh[base]);
      gld16(wf + boff, &shB[base]);
      if (kk < 2) gld16(xl + aoff, &shAl[base]);
    }
    __syncthreads();

    f16x8 afh[4], bf[4];
#pragma unroll
    for (int mt = 0; mt < 4; ++mt)
      afh[mt] = ldh8(&shAh[(wm + mt * 16 + lr) * 32 + qd * 8]);
#pragma unroll
    for (int nt = 0; nt < 4; ++nt)
      bf[nt] = ldh8(&shB[(wn + nt * 16 + lr) * 32 + qd * 8]);
    if (kk < 2) {
      f16x8 afl[4];
#pragma unroll
      for (int mt = 0; mt < 4; ++mt)
        afl[mt] = ldh8(&shAl[(wm + mt * 16 + lr) * 32 + qd * 8]);
#pragma unroll
      for (int mt = 0; mt < 4; ++mt)
#pragma unroll
        for (int nt = 0; nt < 4; ++nt) {
          acc[mt][nt] = __builtin_amdgcn_mfma_f32_16x16x32_f16(afh[mt], bf[nt], acc[mt][nt], 0, 0, 0);
          acc[mt][nt] = __builtin_amdgcn_mfma_f32_16x16x32_f16(afl[mt], bf[nt], acc[mt][nt], 0, 0, 0);
        }
    } else {
#pragma unroll
      for (int mt = 0; mt < 4; ++mt)
#pragma unroll
        for (int nt = 0; nt < 4; ++nt)
          acc[mt][nt] = __builtin_amdgcn_mfma_f32_16x16x32_f16(afh[mt], bf[nt], acc[mt][nt], 0, 0, 0);
    }
    __syncthreads();
  }

  // epilogue: fp16 into LDS transpose buffer -> coalesced 16B stores
  const int b = m0 >> 11;
  const int t0 = m0 & (Tn - 1);
  const float qscale = (kk == 0) ? 8.0f : 1.0f;  // fold *sqrt(d) into Q
#pragma unroll
  for (int mt = 0; mt < 4; ++mt)
#pragma unroll
    for (int nt = 0; nt < 4; ++nt)
#pragma unroll
      for (int r = 0; r < 4; ++r) {
        const int ml = wm + mt * 16 + qd * 4 + r;  // C/D row=(lane>>4)*4+reg
        const int cl = wn + nt * 16 + lr;          // C/D col=lane&15
        smem[ml * TS + cl] = f2h(acc[mt][nt][r] * qscale);
      }
  __syncthreads();

  unsigned short* dst = (kk == 0) ? Qf : (kk == 1) ? Kf : Vf;
  if (kk < 2) {
#pragma unroll
    for (int p = 0; p < 8; ++p) {
      const int s = p * 256 + tid;
      const int tl = s >> 4, sub = s & 15;
      const int hl = sub >> 3, oct = sub & 7;
      const u16x8 v = *reinterpret_cast<const u16x8*>(&smem[tl * TS + hl * 64 + oct * 8]);
      *reinterpret_cast<u16x8*>(
          dst + ((size_t)(b * Hn + hh0 + hl) * Tn + t0 + tl) * Dn + oct * 8) = v;
    }
  } else {
#pragma unroll
    for (int p = 0; p < 8; ++p) {
      const int s = p * 256 + tid;
      const int cl = s >> 4, oct = s & 15;
      const int hl = cl >> 6, dd = cl & 63;
      u16x8 v;
#pragma unroll
      for (int j = 0; j < 8; ++j) v[j] = smem[(oct * 8 + j) * TS + cl];
      *reinterpret_cast<u16x8*>(
          dst + ((size_t)((b * Hn + hh0 + hl) * Dn + dd)) * Tn + t0 + oct * 8) = v;
    }
  }
}

// Flash attention, fp16 energy, j-tile 128, chunked P (small LDS -> 4 blk/CU),
// row-sum via MFMA ones-trick. Qf(x8),Kf: [b,h,t,d]  Vf: [b,h,d,t]  AO: fp16.
__global__ __launch_bounds__(256) void attn_kernel(
    const unsigned short* __restrict__ Qf, const unsigned short* __restrict__ Kf,
    const unsigned short* __restrict__ Vf, unsigned short* __restrict__ AOf)
{
  __shared__ unsigned short shK[2 * 128 * 32];  // [kc][j row][32]  16 KB
  __shared__ unsigned short shV[4 * 64 * 32];   // [kcv][dd][32]    16 KB
  __shared__ unsigned short shP[4 * 16 * PS];   // per-wave 16x32 chunk, 5 KB
  const int tid = threadIdx.x;
  const int w = tid >> 6, L = tid & 63, qd = L >> 4, lr = L & 15;
  const int q0 = blockIdx.x * 64;
  const int bh = blockIdx.y;
  unsigned short* myP = &shP[w * 16 * PS];

  f16x8 aq[2];
  {
    const size_t qoff = ((size_t)bh * Tn + q0 + w * 16 + lr) * Dn;
    aq[0] = ldh8(Qf + qoff + qd * 8);
    aq[1] = ldh8(Qf + qoff + 32 + qd * 8);
  }
  f16x8 ones;
#pragma unroll
  for (int j = 0; j < 8; ++j) ones[j] = (_Float16)1.0f;

  f32x4 oacc[4] = {};
  float mrow[4] = {-1e30f, -1e30f, -1e30f, -1e30f};
  float lsum[4] = {0.f, 0.f, 0.f, 0.f};

  for (int j0 = 0; j0 < Tn; j0 += 128) {
    // stage K tile (128 j x 64 d) as [kc][row][32]
#pragma unroll
    for (int p = 0; p < 4; ++p) {
      const int kc = p >> 1, half = p & 1;
      const int row = half * 64 + (tid >> 2);
      const int slot = tid & 3;
      gld16(Kf + ((size_t)bh * Tn + j0 + row) * Dn + kc * 32 + slot * 8,
            &shK[kc * 4096 + (half * 64 + w * 16) * 32]);
    }
    // stage V tile (64 d x 128 t) as [kcv][dd][32]
#pragma unroll
    for (int p = 0; p < 4; ++p) {
      const int dd = tid >> 2, slot = tid & 3;
      gld16(Vf + ((size_t)bh * Dn + dd) * Tn + j0 + p * 32 + slot * 8,
            &shV[p * 2048 + (w * 16) * 32]);
    }
    __syncthreads();

    // S = Q K^T (Q pre-scaled by 8): 8 col-blocks of 16
    f32x4 s[8];
#pragma unroll
    for (int ct = 0; ct < 8; ++ct) {
      s[ct] = f32x4{0.f, 0.f, 0.f, 0.f};
      const int rk = ct * 16 + lr;
#pragma unroll
      for (int kc = 0; kc < 2; ++kc) {
        const f16x8 bk = ldh8(&shK[kc * 4096 + rk * 32 + qd * 8]);
        s[ct] = __builtin_amdgcn_mfma_f32_16x16x32_f16(aq[kc], bk, s[ct], 0, 0, 0);
      }
    }

    // row max over 128 cols (only remaining shfl reduction)
    float tmax[4];
#pragma unroll
    for (int r = 0; r < 4; ++r) {
      tmax[r] = s[0][r];
#pragma unroll
      for (int ct = 1; ct < 8; ++ct) tmax[r] = fmaxf(tmax[r], s[ct][r]);
    }
#pragma unroll
    for (int x = 1; x < 16; x <<= 1)
#pragma unroll
      for (int r = 0; r < 4; ++r) tmax[r] = fmaxf(tmax[r], __shfl_xor(tmax[r], x, 64));

    float alpha[4];
#pragma unroll
    for (int r = 0; r < 4; ++r) {
      const float mn = fmaxf(mrow[r], tmax[r]);
      alpha[r] = exp2f((mrow[r] - mn) * LOG2E);
      mrow[r] = mn;
    }
#pragma unroll
    for (int ct = 0; ct < 8; ++ct)
#pragma unroll
      for (int r = 0; r < 4; ++r)
        s[ct][r] = exp2f((s[ct][r] - mrow[r]) * LOG2E);  // arg <= 0
#pragma unroll
    for (int nt = 0; nt < 4; ++nt)
#pragma unroll
      for (int r = 0; r < 4; ++r) oacc[nt][r] *= alpha[r];

    // chunked P: per 32-col chunk, C-layout -> LDS -> A-layout, PV + sum MFMA
    f32x4 sacc = {};
#pragma unroll
    for (int kcv = 0; kcv < 4; ++kcv) {
#pragma unroll
      for (int ct2 = 0; ct2 < 2; ++ct2)
#pragma unroll
        for (int r = 0; r < 4; ++r)
          myP[(qd * 4 + r) * PS + ct2 * 16 + lr] = f2h(s[kcv * 2 + ct2][r]);
      const f16x8 pa = ldh8(&myP[lr * PS + qd * 8]);
#pragma unroll
      for (int nt = 0; nt < 4; ++nt) {
        const f16x8 bv = ldh8(&shV[kcv * 2048 + (nt * 16 + lr) * 32 + qd * 8]);
        oacc[nt] = __builtin_amdgcn_mfma_f32_16x16x32_f16(pa, bv, oacc[nt], 0, 0, 0);
      }
      sacc = __builtin_amdgcn_mfma_f32_16x16x32_f16(pa, ones, sacc, 0, 0, 0);
    }
#pragma unroll
    for (int r = 0; r < 4; ++r) lsum[r] = lsum[r] * alpha[r] + sacc[r];
    __syncthreads();
  }

  const int b = bh >> 4, h = bh & 15;
#pragma unroll
  for (int nt = 0; nt < 4; ++nt)
#pragma unroll
    for (int r = 0; r < 4; ++r) {
      const int trow = q0 + w * 16 + qd * 4 + r;
      const int col = h * 64 + nt * 16 + lr;
      AOf[((size_t)b * Tn + trow) * En + col] = f2h(oacc[nt][r] / lsum[r]);
    }
}

// Out-projection: OUT f32; A = AO fp16, B = wout fp16 (pre-cast).
__global__ __launch_bounds__(256) void gemm_out(
    const unsigned short* __restrict__ A, const unsigned short* __restrict__ Bm,
    float* __restrict__ C, int M, int N, int K)
{
  __shared__ unsigned short shA[128 * 32];
  __shared__ unsigned short shB[128 * 32];
  const int tid = threadIdx.x;
  const int w = tid >> 6, L = tid & 63, qd = L >> 4, lr = L & 15;
  const int m0 = blockIdx.y * 128;
  const int n0 = blockIdx.x * 128;
  const int wm = (w >> 1) * 64, wn = (w & 1) * 64;

  f32x4 acc[4][4] = {};

  for (int k0 = 0; k0 < K; k0 += 32) {
#pragma unroll
    for (int p = 0; p < 2; ++p) {
      const int c = p * 256 + tid;
      const int row = c >> 2, slot = c & 3;
      const int base = (p * 4 + w) * 512;
      gld16(A + (size_t)(m0 + row) * K + k0 + slot * 8, &shA[base]);
      gld16(Bm + (size_t)(n0 + row) * K + k0 + slot * 8, &shB[base]);
    }
    __syncthreads();

    f16x8 af[4], bf[4];
#pragma unroll
    for (int mt = 0; mt < 4; ++mt)
      af[mt] = ldh8(&shA[(wm + mt * 16 + lr) * 32 + qd * 8]);
#pragma unroll
    for (int nt = 0; nt < 4; ++nt)
      bf[nt] = ldh8(&shB[(wn + nt * 16 + lr) * 32 + qd * 8]);
#pragma unroll
    for (int mt = 0; mt < 4; ++mt)
#pragma unroll
      for (int nt = 0; nt < 4; ++nt)
        acc[mt][nt] = __builtin_amdgcn_mfma_f32_16x16x32_f16(af[mt], bf[nt], acc[mt][nt], 0, 0, 0);
    __syncthreads();
  }

#pragma unroll
  for (int mt = 0; mt < 4; ++mt)
#pragma unroll
    for (int nt = 0; nt < 4; ++nt)
#pragma unroll
      for (int r = 0; r < 4; ++r) {
        const int m = m0 + wm + mt * 16 + qd * 4 + r;
        const int n = n0 + wn + nt * 16 + lr;
        C[(size_t)m * N + n] = acc[mt][nt][r];
      }
}

extern "C" void kernel_launch(void* const* d_in, const int* in_sizes, int n_in,
                              void* d_out, int out_size, void* d_ws, size_t ws_size,
                              hipStream_t stream) {
  (void)in_sizes; (void)n_in; (void)out_size; (void)ws_size;
  const float* x = (const float*)d_in[0];      // [2,2048,1024] f32
  const float* wqkv = (const float*)d_in[1];   // [3072,1024]  f32
  const float* wout = (const float*)d_in[2];   // [1024,1024]  f32
  float* out = (float*)d_out;                  // [2,2048,1024] f32

  const size_t elems = (size_t)Bn * Hn * Tn * Dn;  // 4M elems (8 MiB fp16)
  unsigned short* Qf = (unsigned short*)d_ws;
  unsigned short* Kf = Qf + elems;
  unsigned short* Vf = Kf + elems;
  unsigned short* AOf = Vf + elems;
  unsigned short* wf = AOf + elems;                // fp16 w_qkv, 3M
  unsigned short* wof = wf + (size_t)3 * En * En;  // fp16 wout, 1M (40 MiB)

  // d_out (16 MiB) doubles as scratch for x hi/lo; overwritten by gemm_out.
  unsigned short* xh = (unsigned short*)d_out;
  unsigned short* xl = xh + elems;

  const int M = Bn * Tn;  // 4096
  dim3 blk(256);
  split_f32_f16<<<dim3((int)(elems / 1024)), blk, 0, stream>>>(x, xh, xl);
  cvt_f32_f16<<<dim3(3 * En * En / 1024), blk, 0, stream>>>(wqkv, wf);
  cvt_f32_f16<<<dim3(En * En / 1024), blk, 0, stream>>>(wout, wof);
  gemm_qkv<<<dim3(24, M / 128), blk, 0, stream>>>(
      xh, xl, wf, Qf, Kf, Vf, M, En);
  attn_kernel<<<dim3(Tn / 64, Bn * Hn), blk, 0, stream>>>(Qf, Kf, Vf, AOf);
  gemm_out<<<dim3(En / 128, M / 128), blk, 0, stream>>>(
      AOf, wof, out, M, En, En);
}